// Round 3
// baseline (7228.558 us; speedup 1.0000x reference)
//
#include <hip/hip_runtime.h>
#include <hip/hip_bf16.h>

// ---------------------------------------------------------------------------
// Sophie on MI355X, round 18: PERSISTENT kernel, conservative coherence.
// Compute paths are BYTE-IDENTICAL to R16 (the passing 2184us kernel):
// plain stores, global_load_lds aux=0, original att + epilogues.
// 64 launches -> 1 regular launch of main_kernel<<<458,256>>> with a
// grid barrier that emulates a kernel boundary exactly:
//   syncthreads (drain vmcnt) -> threadfence (release: L2 writeback) ->
//   atomicAdd arrive -> spin on generation (relaxed agent load) ->
//   threadfence (acquire: L1/L2 invalidate) -> syncthreads.
// This is the same threadfence+device-atomic protocol R16's att finalize
// already uses cross-XCD (measured-correct, absmax 4.88e-4).
// Residency: LDS 69.9KB/block -> 2 blocks/CU; launch_bounds(256,2) caps
// VGPR<=256 -> 512 slots >= 458 blocks, all co-resident (dedicated GPU).
// Only non-R16 delta in att: cnt reset via atomicExch (plain store would
// sit dirty in one XCD's L2 while next step's atomicAdds hit LLC).
// ---------------------------------------------------------------------------

typedef __bf16 bf16x8 __attribute__((ext_vector_type(8)));
typedef float  f32x4  __attribute__((ext_vector_type(4)));

#define KD 512

__device__ __forceinline__ void gl_lds16(const void* g, void* l) {
  __builtin_amdgcn_global_load_lds(
      (const __attribute__((address_space(1))) void*)g,
      (__attribute__((address_space(3))) void*)l, 16, 0, 0);
}
__device__ __forceinline__ float sigm(float x) {
  return __builtin_amdgcn_rcpf(1.f + __expf(-x));
}
__device__ __forceinline__ float tanh_f(float x) {
  return 2.f * __builtin_amdgcn_rcpf(1.f + __expf(-2.f * x)) - 1.f;
}
__device__ __forceinline__ float sel4(f32x4 v, int i) {
  float a = (i & 1) ? v[1] : v[0];
  float b = (i & 1) ? v[3] : v[2];
  return (i & 2) ? b : a;
}
__device__ __forceinline__ float pick(int m, float o0, float o1, float o2, float o3) {
  float a = (m & 1) ? o1 : o0;
  float b = (m & 1) ? o3 : o2;
  return (m & 2) ? b : a;
}

struct SP {
  const unsigned short* Wp;        // [224 ntg][64 kg][16 nn][8 j]: gates|wk|wv|wq
  unsigned short* A0; unsigned short* A1;   // [4224][512] bf16
  __bf16* Zb0; __bf16* Zb1;        // [4096][1024] bf16: k|v bias-folded
  float* q0; float* q1;            // [512] fp32 q bias-folded
  __bf16* coB;                     // [4224][512] bf16 cell state
  float* ht;                       // [65][512]
  const float* biasz;              // [1536] bk|bv|bq
  const float4* bs4; const float4* w04; const float4* w14;
  const float* others; const float* target;
  const float* scene; const float* out_w; const float* out_b;
  float* part; unsigned int* cnt;
  unsigned int* bar;               // [0]=arrive count, [1]=generation
  float* out;
};

// ---------------------------------------------------------------------------
// Grid barrier emulating a kernel boundary (all-resident grid).
// Release: threadfence (waitcnt + L2 writeback) before arrive-add.
// Acquire: threadfence (L1/L2 invalidate) after generation observed.
// ---------------------------------------------------------------------------
__device__ __forceinline__ void gridbar(unsigned int* bar, unsigned int nb,
                                        unsigned int g) {
  __syncthreads();                     // all waves' stores drained to L2
  if (threadIdx.x == 0) {
    __threadfence();                   // release: flush this XCD's dirty L2
    unsigned int old = atomicAdd(bar, 1u);
    if (old == nb - 1u) {
      atomicExch(bar, 0u);             // reset for next generation
      __threadfence();
      atomicExch(bar + 1, g);          // publish generation
    } else {
      while (__hip_atomic_load(bar + 1, __ATOMIC_RELAXED,
                               __HIP_MEMORY_SCOPE_AGENT) < g)
        __builtin_amdgcn_s_sleep(2);
    }
    __threadfence();                   // acquire: invalidate stale L1/L2
  }
  __syncthreads();
}

// ---------------------------------------------------------------------------
// One 128x256 GEMM tile for step p + fused epilogue. BK=128.  (R16 verbatim)
// LDS buffer layout: [row 0..127][granule 0..15] where LDS granule g of row r
// holds global k-granule (g ^ (r & 15)) (16B granules, 8 bf16 each).
// ---------------------------------------------------------------------------
__device__ void do_gemm(const SP& P, int p, int bm, int bn)
{
  __shared__ __align__(16) char aLds[2][128 * 128 * 2];   // 2 x 32 KB

  const int tid = threadIdx.x, wave = tid >> 6, lane = tid & 63;
  const unsigned short* A = (p & 1) ? P.A1 : P.A0;
  __bf16* An = (__bf16*)((p & 1) ? P.A0 : P.A1);
  __bf16* Zb = (p & 1) ? P.Zb1 : P.Zb0;
  float* qv  = (p & 1) ? P.q1 : P.q0;
  const int tin = (p + 1 < 31) ? (p + 1) : 31;
  const int tc  = (p + 1 < 63) ? (p + 1) : 63;
  const float* op = P.others + (size_t)tin * 8192;
  const float* tp = P.target + tc * 2;
  float* htn = P.ht + (size_t)(p + 1) * 512;

  const int m0 = bm * 128;
  const int l15 = lane & 15, lq = lane >> 4;

  // A staging: 32 chunks of 1KB per 128-wide K-iter; wave stages 8 chunks.
  int aRow[8], aOff[8], ldsOff[8];
#pragma unroll
  for (int j = 0; j < 8; ++j) {
    int chunk = j * 4 + wave;                 // 0..31
    int r = chunk * 4 + (lane >> 4);          // row local 0..127
    int ch = lane & 15;                       // LDS granule slot
    aRow[j]   = m0 + r;
    aOff[j]   = (ch ^ (r & 15)) * 8;          // global elem offset in row
    ldsOff[j] = chunk * 1024;
  }
  const unsigned short* bBase =
      P.Wp + (size_t)(bn * 16 + wave * 4) * 8192 + lq * 128 + l15 * 8;

  f32x4 acc[8][4];
#pragma unroll
  for (int i = 0; i < 8; ++i)
#pragma unroll
    for (int j = 0; j < 4; ++j) acc[i][j] = f32x4{0.f, 0.f, 0.f, 0.f};

  bf16x8 bCur[4], bNext[4];

#pragma unroll
  for (int j = 0; j < 8; ++j)
    gl_lds16(A + (size_t)aRow[j] * KD + aOff[j], aLds[0] + ldsOff[j]);
#pragma unroll
  for (int nt = 0; nt < 4; ++nt)
    bCur[nt] = *(const bf16x8*)(bBase + nt * 8192);     // kc = 0
  __syncthreads();

  for (int it = 0; it < 4; ++it) {
    if (it < 3) {
      const int k1 = (it + 1) * 128;
#pragma unroll
      for (int j = 0; j < 8; ++j)
        gl_lds16(A + (size_t)aRow[j] * KD + k1 + aOff[j],
                 aLds[(it + 1) & 1] + ldsOff[j]);
    }
    const char* buf = aLds[it & 1];
#pragma unroll
    for (int c = 0; c < 4; ++c) {
      const bool hasNext = !(it == 3 && c == 3);
      if (hasNext) {
        const int nkc = it * 4 + c + 1;       // next K-chunk (K=32 units)
#pragma unroll
        for (int nt = 0; nt < 4; ++nt)
          bNext[nt] = *(const bf16x8*)(bBase + nt * 8192 + nkc * 512);
      }
      bf16x8 af[8];
#pragma unroll
      for (int mt = 0; mt < 8; ++mt) {
        int row = mt * 16 + l15;
        int g = (c * 4 + lq) ^ (row & 15);
        af[mt] = *(const bf16x8*)(buf + row * 256 + g * 16);
      }
#pragma unroll
      for (int mt = 0; mt < 8; ++mt)
#pragma unroll
        for (int nt = 0; nt < 4; ++nt)
          acc[mt][nt] = __builtin_amdgcn_mfma_f32_16x16x32_bf16(
              af[mt], bCur[nt], acc[mt][nt], 0, 0, 0);
      if (hasNext) {
#pragma unroll
        for (int nt = 0; nt < 4; ++nt) bCur[nt] = bNext[nt];
      }
    }
    __syncthreads();
  }
  // K-loop done; aLds free for epilogue staging.

  const int rq = lq * 4;

  if (bn >= 12) {
    // ---- q epilogue: row 4096 only (bm==32 tiles) ----
    if (lq == 0) {
#pragma unroll
      for (int nt = 0; nt < 4; ++nt) {
        int qcol = (bn - 12) * 256 + wave * 64 + nt * 16 + l15;
        qv[qcol] = acc[0][nt][0] + P.biasz[1024 + qcol];
      }
    }
    return;
  }

  if (bn >= 8) {
    // ---- k/v epilogue: LDS transpose -> coalesced 16B stores, 2 halves ----
    __bf16* zT = (__bf16*)aLds;          // [64][256] per half (32 KB)
    const int zbase = (bn - 8) * 256;
    float bias[4];
#pragma unroll
    for (int nt = 0; nt < 4; ++nt)
      bias[nt] = P.biasz[zbase + wave * 64 + nt * 16 + l15];
#pragma unroll
    for (int half = 0; half < 2; ++half) {
#pragma unroll
      for (int mt2 = 0; mt2 < 4; ++mt2) {
        int mt = half * 4 + mt2;
#pragma unroll
        for (int nt = 0; nt < 4; ++nt) {
          int ulocal = wave * 64 + nt * 16 + l15;
#pragma unroll
          for (int r = 0; r < 4; ++r) {
            int rloc = mt2 * 16 + rq + r;
            zT[rloc * 256 + ulocal] = (__bf16)(acc[mt][nt][r] + bias[nt]);
          }
        }
      }
      __syncthreads();
      const bf16x8* zc = (const bf16x8*)zT;
#pragma unroll
      for (int i = 0; i < 8; ++i) {
        int idx = i * 256 + tid;
        int rloc = idx >> 5, c8 = idx & 31;
        *(bf16x8*)(Zb + (size_t)(m0 + half * 64 + rloc) * 1024 + zbase + c8 * 8) = zc[idx];
      }
      __syncthreads();
    }
    return;
  }

  // ---- gate epilogue: fused LSTM cell (R13 form) ----
  const int rho = lane & 3, usel = (lane >> 2) & 3;
  const int u0 = bn * 64 + wave * 16;
  float4 bsv[4], w0v[4], w1v[4];
  int uu[4];
#pragma unroll
  for (int nt = 0; nt < 4; ++nt) {
    uu[nt]  = u0 + nt * 4 + usel;
    bsv[nt] = P.bs4[uu[nt]];
    w0v[nt] = P.w04[uu[nt]];
    w1v[nt] = P.w14[uu[nt]];
  }

  if (bm < 32) {
    __bf16* hT = (__bf16*)aLds[0];       // [128][64]
    __bf16* cT = (__bf16*)aLds[1];       // [128][64]
#pragma unroll
    for (int mt = 0; mt < 8; ++mt) {
      int rloc = mt * 16 + rq + rho;
      int row  = m0 + rloc;
      float x0 = op[2 * row], x1 = op[2 * row + 1];
#pragma unroll
      for (int nt = 0; nt < 4; ++nt) {
        f32x4 v = acc[mt][nt];
        float own = sel4(v, rho);
        float r1  = __shfl_xor(sel4(v, rho ^ 1), 1, 64);
        float r2  = __shfl_xor(sel4(v, rho ^ 2), 2, 64);
        float r3  = __shfl_xor(sel4(v, rho ^ 3), 3, 64);
        float g0 = pick(rho,     own, r1, r2, r3);
        float g1 = pick(rho ^ 1, own, r1, r2, r3);
        float g2 = pick(rho ^ 2, own, r1, r2, r3);
        float g3 = pick(rho ^ 3, own, r1, r2, r3);
        float4 bs = bsv[nt], w0 = w0v[nt], w1 = w1v[nt];
        float p0 = g0 + bs.x + w0.x * x0 + w1.x * x1;
        float p1 = g1 + bs.y + w0.y * x0 + w1.y * x1;
        float p2 = g2 + bs.z + w0.z * x0 + w1.z * x1;
        float p3 = g3 + bs.w + w0.w * x0 + w1.w * x1;
        int u = uu[nt];
        size_t ci = (size_t)row * 512 + u;
        float c_old = (float)P.coB[ci];
        float ii = sigm(p0), ff = sigm(p1), gg = tanh_f(p2), oo = sigm(p3);
        float cn = ff * c_old + ii * gg;
        float h  = oo * tanh_f(cn);
        int ulocal = u - bn * 64;
        hT[rloc * 64 + ulocal] = (__bf16)h;
        cT[rloc * 64 + ulocal] = (__bf16)cn;
      }
    }
    __syncthreads();
    const bf16x8* hc = (const bf16x8*)hT;
    const bf16x8* cc = (const bf16x8*)cT;
#pragma unroll
    for (int i = 0; i < 4; ++i) {
      int idx = i * 256 + tid;
      int rloc = idx >> 3, c8 = idx & 7;
      size_t base = (size_t)(m0 + rloc) * 512 + bn * 64 + c8 * 8;
      *(bf16x8*)(An + base)    = hc[idx];
      *(bf16x8*)(P.coB + base) = cc[idx];
    }
    return;
  }

  // bm == 32: only row 4096 valid
#pragma unroll
  for (int mt = 0; mt < 8; ++mt) {
    int row = m0 + mt * 16 + rq + rho;
    bool act = row <= 4096;
    float x0 = 0.f, x1 = 0.f;
    if (act) {
      if (row < 4096) { x0 = op[2 * row]; x1 = op[2 * row + 1]; }
      else            { x0 = tp[0];       x1 = tp[1]; }
    }
#pragma unroll
    for (int nt = 0; nt < 4; ++nt) {
      f32x4 v = acc[mt][nt];
      float own = sel4(v, rho);
      float r1  = __shfl_xor(sel4(v, rho ^ 1), 1, 64);
      float r2  = __shfl_xor(sel4(v, rho ^ 2), 2, 64);
      float r3  = __shfl_xor(sel4(v, rho ^ 3), 3, 64);
      float g0 = pick(rho,     own, r1, r2, r3);
      float g1 = pick(rho ^ 1, own, r1, r2, r3);
      float g2 = pick(rho ^ 2, own, r1, r2, r3);
      float g3 = pick(rho ^ 3, own, r1, r2, r3);
      if (act) {
        float4 bs = bsv[nt], w0 = w0v[nt], w1 = w1v[nt];
        float p0 = g0 + bs.x + w0.x * x0 + w1.x * x1;
        float p1 = g1 + bs.y + w0.y * x0 + w1.y * x1;
        float p2 = g2 + bs.z + w0.z * x0 + w1.z * x1;
        float p3 = g3 + bs.w + w0.w * x0 + w1.w * x1;
        int u = uu[nt];
        size_t ci = (size_t)row * 512 + u;
        float c_old = (float)P.coB[ci];
        float ii = sigm(p0), ff = sigm(p1), gg = tanh_f(p2), oo = sigm(p3);
        float cn = ff * c_old + ii * gg;
        float h  = oo * tanh_f(cn);
        P.coB[ci] = (__bf16)cn;
        An[ci] = (__bf16)h;
        if (row == 4096) htn[u] = h;
      }
    }
  }
}

// ---------------------------------------------------------------------------
// Attention for step p, task b (64 tasks x 64 rows) + last-done finalize.
// (R16 verbatim, except cnt reset is atomicExch for persistent-kernel reuse.)
// ---------------------------------------------------------------------------
__device__ void do_att(const SP& P, int p, int b)
{
  __shared__ __align__(16) float qs[512];
  __shared__ float red[256];
  __shared__ float red2[256];
  __shared__ float es[64];
  __shared__ unsigned int sOld;
  const int t = threadIdx.x;
  const __bf16* Zb = (p & 1) ? P.Zb1 : P.Zb0;
  const float* qv  = (p & 1) ? P.q1 : P.q0;
  const float* ht  = P.ht + (size_t)p * 512;

  for (int c = t; c < 512; c += 256) qs[c] = qv[c];
  __syncthreads();

  const int r0 = b * 64, rl = t >> 2, p4 = t & 3;
  const bf16x8* krow = (const bf16x8*)(Zb + (size_t)(r0 + rl) * 1024);
  float a = 0.f;
  for (int i = p4; i < 64; i += 4) {
    bf16x8 kk = krow[i];
    const float* qq = qs + i * 8;
#pragma unroll
    for (int j = 0; j < 8; ++j) a += (float)kk[j] * qq[j];
  }
  red[t] = a;
  __syncthreads();
  if (t < 64)
    es[t] = __expf((red[4 * t] + red[4 * t + 1] + red[4 * t + 2] + red[4 * t + 3]) *
                   0.04419417382415922f);
  __syncthreads();

  float s0 = 0.f, s1 = 0.f;
  for (int r = 0; r < 64; ++r) {
    const __bf16* vr = Zb + (size_t)(r0 + r) * 1024 + 512;
    float e = es[r];
    s0 += e * (float)vr[t];
    s1 += e * (float)vr[t + 256];
  }
  P.part[b * 513 + t] = s0;
  P.part[b * 513 + 256 + t] = s1;
  if (t == 0) {
    float se = 0.f;
#pragma unroll
    for (int r = 0; r < 64; ++r) se += es[r];
    P.part[b * 513 + 512] = se;
  }
  __threadfence();
  __syncthreads();
  if (t == 0) sOld = atomicAdd(P.cnt, 1u);
  __syncthreads();
  if (sOld == 63) {
    __threadfence();
    float s = 0.f, s2 = 0.f, se = 0.f;
    for (int bb = 0; bb < 64; ++bb) {
      s  += P.part[bb * 513 + t];
      s2 += P.part[bb * 513 + 256 + t];
      se += P.part[bb * 513 + 512];
    }
    float inv = 1.f / se;
    float va = ht[t] + s * inv + P.scene[t];
    float vb = ht[t + 256] + s2 * inv + P.scene[t + 256];
    red[t]  = va * P.out_w[t]       + vb * P.out_w[t + 256];
    red2[t] = va * P.out_w[512 + t] + vb * P.out_w[768 + t];
    __syncthreads();
    for (int st = 128; st > 0; st >>= 1) {
      if (t < st) { red[t] += red[t + st]; red2[t] += red2[t + st]; }
      __syncthreads();
    }
    if (t == 0) {
      P.out[2 * p]     = red[0]  + P.out_b[0];
      P.out[2 * p + 1] = red2[0] + P.out_b[1];
      atomicExch(P.cnt, 0u);
    }
  }
}

// ---------------------------------------------------------------------------
// Persistent kernel: 458 blocks, 64 steps, grid barrier between steps.
// Block role fixed for the whole run (R16 decode):
//   w = xcd*57 + min(xcd,2) + slot (bijective over [0,458)).
//   w < 448: bm = w/14, j = w%14; j<12 -> gemm(bm,j); j in {12,13} -> att
//   task 2*bm+(j-12) for step p-1. w >= 448: bm=32 tail tiles (gates + q).
// ---------------------------------------------------------------------------
__global__ __launch_bounds__(256, 2) void main_kernel(SP P)
{
  const int xcd  = blockIdx.x & 7;
  const int slot = blockIdx.x >> 3;
  const int w = xcd * 57 + (xcd < 2 ? xcd : 2) + slot;

  int bm = 0, bn = 0, attTask = -1;
  if (w < 448) {
    bm = w / 14;
    int j = w % 14;
    if (j < 12) bn = j;
    else attTask = 2 * bm + (j - 12);
  } else {
    int ti = w - 448;
    bm = 32;
    bn = (ti < 8) ? ti : (12 + (ti - 8));
  }

  for (int p = 0; p < 64; ++p) {
    if (attTask >= 0) {
      if (p >= 1) do_att(P, p - 1, attTask);
    } else {
      do_gemm(P, p, bm, bn);
    }
    gridbar(P.bar, 458u, (unsigned int)(p + 1));
  }
  if (attTask >= 0) do_att(P, 63, attTask);
}

// ---------------------------------------------------------------------------
// Prep kernels (R16 verbatim; init_state also zeroes barrier words).
// ---------------------------------------------------------------------------
__global__ __launch_bounds__(256) void init_state(
    const float* __restrict__ others0, const float* __restrict__ target0,
    const float* __restrict__ w_ih, const float* __restrict__ b_ih,
    const float* __restrict__ b_hh,
    __bf16* __restrict__ coB, __bf16* __restrict__ A0, float* __restrict__ ht0,
    unsigned int* __restrict__ cnt)
{
  int g = blockIdx.x * 256 + threadIdx.x;
  if (g == 0) { cnt[0] = 0u; cnt[16] = 0u; cnt[17] = 0u; }
  if (g >= 4097 * 512) return;
  int r = g >> 9, j = g & 511;
  float x0, x1;
  if (r < 4096) { x0 = others0[2 * r]; x1 = others0[2 * r + 1]; }
  else          { x0 = target0[0];     x1 = target0[1]; }
  float pre[4];
#pragma unroll
  for (int gg = 0; gg < 4; ++gg) {
    int n = gg * 512 + j;
    pre[gg] = b_ih[n] + b_hh[n] + w_ih[2 * n] * x0 + w_ih[2 * n + 1] * x1;
  }
  float cn = sigm(pre[0]) * tanh_f(pre[2]);
  float h  = sigm(pre[3]) * tanh_f(cn);
  coB[g] = (__bf16)cn;
  A0[g] = (__bf16)h;
  if (r == 4096) ht0[j] = h;
}

__global__ __launch_bounds__(256) void pack_w(
    const float* __restrict__ w_hh, const float* __restrict__ wk,
    const float* __restrict__ wv,   const float* __restrict__ wq,
    __bf16* __restrict__ Wp)
{
  int o = blockIdx.x * 256 + threadIdx.x;   // 1,835,008
  int j = o & 7, nn = (o >> 3) & 15, kg = (o >> 7) & 63, ntg = o >> 13;
  int n = ntg * 16 + nn, k = kg * 8 + j;
  float v;
  if (n < 2048)      { int u = n >> 2, g = n & 3; v = w_hh[(g * 512 + u) * 512 + k]; }
  else if (n < 2560) v = wk[(n - 2048) * 512 + k];
  else if (n < 3072) v = wv[(n - 2560) * 512 + k];
  else               v = wq[(n - 3072) * 512 + k];
  Wp[o] = (__bf16)v;
}

__global__ __launch_bounds__(256) void pack_misc(
    const float* __restrict__ b_ih, const float* __restrict__ b_hh,
    const float* __restrict__ w_ih,
    const float* __restrict__ bk, const float* __restrict__ bv,
    const float* __restrict__ bq,
    float* __restrict__ bs, float* __restrict__ w0, float* __restrict__ w1,
    float* __restrict__ biasz)
{
  int i = blockIdx.x * 256 + threadIdx.x;
  if (i < 2048) {
    int u = i >> 2, g = i & 3, n = g * 512 + u;
    bs[i] = b_ih[n] + b_hh[n];
    w0[i] = w_ih[2 * n];
    w1[i] = w_ih[2 * n + 1];
  } else if (i < 2048 + 1536) {
    int z = i - 2048;
    biasz[z] = (z < 512) ? bk[z] : (z < 1024 ? bv[z - 512] : bq[z - 1024]);
  }
}

__global__ __launch_bounds__(256) void scene1_kernel(
    const int* __restrict__ map, const float* __restrict__ emb,
    const float* __restrict__ w1, const float* __restrict__ b1,
    float* __restrict__ out1)
{
  __shared__ float wl[576];
  __shared__ float bl[16];
  const int t = threadIdx.x;
  for (int i = t; i < 576; i += 256) wl[i] = w1[i];
  if (t < 16) bl[t] = b1[t];
  __syncthreads();
  const int y = blockIdx.x, x = t;
  float nb[4][9];
#pragma unroll
  for (int dy = 0; dy < 3; ++dy)
#pragma unroll
    for (int dx = 0; dx < 3; ++dx) {
      int yy = y + dy - 1, xx = x + dx - 1;
      bool ok = (yy >= 0 && yy < 256 && xx >= 0 && xx < 256);
      int m = ok ? map[yy * 256 + xx] : 0;
#pragma unroll
      for (int c = 0; c < 4; ++c)
        nb[c][dy * 3 + dx] = ok ? emb[m * 4 + c] : 0.f;
    }
  for (int oc = 0; oc < 16; ++oc) {
    float a = bl[oc];
#pragma unroll
    for (int c = 0; c < 4; ++c)
#pragma unroll
      for (int k = 0; k < 9; ++k) a += wl[(oc * 4 + c) * 9 + k] * nb[c][k];
    out1[oc * 65536 + y * 256 + x] = fmaxf(a, 0.f);
  }
}

__global__ __launch_bounds__(256) void scene2_kernel(
    const float* __restrict__ out1, const float* __restrict__ w2,
    const float* __restrict__ b2, float* __restrict__ rowpart)
{
  __shared__ float wl[1152];
  __shared__ float lds4[4 * 8];
  const int t = threadIdx.x;
  const int y = blockIdx.x & 255, ocg = blockIdx.x >> 8;
  for (int i = t; i < 1152; i += 256) wl[i] = w2[ocg * 1152 + i];
  __syncthreads();
  const int x = t;
  float acc[8];
#pragma unroll
  for (int o = 0; o < 8; ++o) acc[o] = b2[ocg * 8 + o];
  for (int ic = 0; ic < 16; ++ic) {
    float nb[9];
#pragma unroll
    for (int dy = 0; dy < 3; ++dy)
#pragma unroll
      for (int dx = 0; dx < 3; ++dx) {
        int yy = y + dy - 1, xx = x + dx - 1;
        bool ok = (yy >= 0 && yy < 256 && xx >= 0 && xx < 256);
        nb[dy * 3 + dx] = ok ? out1[ic * 65536 + yy * 256 + xx] : 0.f;
      }
#pragma unroll
    for (int o = 0; o < 8; ++o) {
      const float* w = &wl[(o * 16 + ic) * 9];
#pragma unroll
      for (int k = 0; k < 9; ++k) acc[o] += w[k] * nb[k];
    }
  }
  const int wave = t >> 6, lane = t & 63;
#pragma unroll
  for (int o = 0; o < 8; ++o) {
    float v = fmaxf(acc[o], 0.f);
#pragma unroll
    for (int m = 1; m < 64; m <<= 1) v += __shfl_xor(v, m, 64);
    if (lane == 0) lds4[wave * 8 + o] = v;
  }
  __syncthreads();
  if (t < 8)
    rowpart[y * 32 + ocg * 8 + t] = lds4[t] + lds4[8 + t] + lds4[16 + t] + lds4[24 + t];
}

__global__ __launch_bounds__(512) void scene3_kernel(
    const float* __restrict__ rowpart, const float* __restrict__ fcw,
    const float* __restrict__ fcb, float* __restrict__ scene)
{
  __shared__ float mean[32];
  const int t = threadIdx.x;
  if (t < 32) {
    float s = 0.f;
    for (int y = 0; y < 256; ++y) s += rowpart[y * 32 + t];
    mean[t] = s * (1.f / 65536.f);
  }
  __syncthreads();
  float a = fcb[t];
#pragma unroll
  for (int c = 0; c < 32; ++c) a += mean[c] * fcw[t * 32 + c];
  scene[t] = a;
}

// ---------------------------------------------------------------------------
extern "C" void kernel_launch(void* const* d_in, const int* in_sizes, int n_in,
                              void* d_out, int out_size, void* d_ws, size_t ws_size,
                              hipStream_t stream) {
  const float* target    = (const float*)d_in[0];
  const float* others    = (const float*)d_in[1];
  const int*   scene_map = (const int*)d_in[2];
  const float* emb       = (const float*)d_in[3];
  const float* c1w       = (const float*)d_in[4];
  const float* c1b       = (const float*)d_in[5];
  const float* c2w       = (const float*)d_in[6];
  const float* c2b       = (const float*)d_in[7];
  const float* fcw       = (const float*)d_in[8];
  const float* fcb       = (const float*)d_in[9];
  const float* w_ih      = (const float*)d_in[10];
  const float* w_hh      = (const float*)d_in[11];
  const float* b_ih      = (const float*)d_in[12];
  const float* b_hh      = (const float*)d_in[13];
  const float* wq        = (const float*)d_in[14];
  const float* bq        = (const float*)d_in[15];
  const float* wk        = (const float*)d_in[16];
  const float* bk        = (const float*)d_in[17];
  const float* wv        = (const float*)d_in[18];
  const float* bv        = (const float*)d_in[19];
  const float* out_w     = (const float*)d_in[20];
  const float* out_b     = (const float*)d_in[21];
  float* out = (float*)d_out;

  char* ws = (char*)d_ws;
  size_t off = 0;
  auto alloc = [&](size_t bytes) { size_t o = off; off += (bytes + 255) & ~(size_t)255; return o; };
  __bf16* Zb0   = (__bf16*)(ws + alloc((size_t)4096 * 1024 * 2));
  __bf16* Zb1   = (__bf16*)(ws + alloc((size_t)4096 * 1024 * 2));
  float*  q0    = (float*)(ws + alloc(512 * 4));
  float*  q1    = (float*)(ws + alloc(512 * 4));
  __bf16* Wp    = (__bf16*)(ws + alloc((size_t)1835008 * 2));
  __bf16* A0    = (__bf16*)(ws + alloc((size_t)4224 * 512 * 2));
  __bf16* A1    = (__bf16*)(ws + alloc((size_t)4224 * 512 * 2));
  __bf16* coB   = (__bf16*)(ws + alloc((size_t)4224 * 512 * 2));
  float*  ht    = (float*)(ws + alloc((size_t)65 * 512 * 4));
  float*  scene = (float*)(ws + alloc(2048));
  float*  part  = (float*)(ws + alloc(64 * 513 * 4));
  unsigned int* cnt = (unsigned int*)(ws + alloc(256));
  float*  bs    = (float*)(ws + alloc(2048 * 4));
  float*  w0p   = (float*)(ws + alloc(2048 * 4));
  float*  w1p   = (float*)(ws + alloc(2048 * 4));
  float*  biasz = (float*)(ws + alloc(1536 * 4));
  float*  out1  = (float*)(ws + alloc((size_t)16 * 65536 * 4));
  float*  rowp  = (float*)(ws + alloc(256 * 32 * 4));

  pack_w<<<7168, 256, 0, stream>>>(w_hh, wk, wv, wq, Wp);
  pack_misc<<<14, 256, 0, stream>>>(b_ih, b_hh, w_ih, bk, bv, bq, bs, w0p, w1p, biasz);
  scene1_kernel<<<256, 256, 0, stream>>>(scene_map, emb, c1w, c1b, out1);
  scene2_kernel<<<1024, 256, 0, stream>>>(out1, c2w, c2b, rowp);
  scene3_kernel<<<1, 512, 0, stream>>>(rowp, fcw, fcb, scene);
  init_state<<<8194, 256, 0, stream>>>(others, target, w_ih, b_ih, b_hh, coB, A0, ht, cnt);

  SP hp;
  hp.Wp = (const unsigned short*)Wp;
  hp.A0 = (unsigned short*)A0; hp.A1 = (unsigned short*)A1;
  hp.Zb0 = Zb0; hp.Zb1 = Zb1;
  hp.q0 = q0; hp.q1 = q1;
  hp.coB = coB; hp.ht = ht;
  hp.biasz = biasz;
  hp.bs4 = (const float4*)bs; hp.w04 = (const float4*)w0p; hp.w14 = (const float4*)w1p;
  hp.others = others; hp.target = target;
  hp.scene = scene; hp.out_w = out_w; hp.out_b = out_b;
  hp.part = part; hp.cnt = cnt;
  hp.bar = cnt + 16;
  hp.out = out;

  main_kernel<<<458, 256, 0, stream>>>(hp);
}

// Round 5
// 3835.793 us; speedup vs baseline: 1.8845x; 1.8845x over previous
//
#include <hip/hip_runtime.h>
#include <hip/hip_bf16.h>

// ---------------------------------------------------------------------------
// Sophie on MI355X, round 20 = R19 (persistent, fence-free) + barrier
// watchdog. R19's container died without diagnostics; the watchdog makes
// any deadlock terminate in bounded time (wrong answer instead of hang).
//  - Read-only (Wp/biases/others/target): PLAIN -> L2-resident all steps.
//  - coB: same-block producer/consumer -> PLAIN, L2-resident.
//  - Cross-block mutable (A, Zb, q, ht, part): agent-scope relaxed
//    atomics (write-through LLC stores / LLC-reading loads) - placement-
//    independent (G16), no fences, no per-step L2 invalidation.
//  - A staging: register-staged agent loads + ds_write (double-buffered,
//    loads for K-block it+1 issued right after barrier, land under MFMA).
//  - Grid barrier: 2-level tree (8 groups x <=64), device atomicAdd,
//    per-group generation lines, vmcnt(0) between protocol phases,
//    2e7-tick spin watchdog (never fires when healthy).
// Arithmetic identical to R16/R13 -> same absmax expected.
// ---------------------------------------------------------------------------

typedef __bf16 bf16x8 __attribute__((ext_vector_type(8)));
typedef float  f32x4  __attribute__((ext_vector_type(4)));
typedef unsigned long long u64;

#define KD 512

struct __attribute__((aligned(16))) U16B { u64 lo, hi; };

__device__ __forceinline__ float sigm(float x) {
  return __builtin_amdgcn_rcpf(1.f + __expf(-x));
}
__device__ __forceinline__ float tanh_f(float x) {
  return 2.f * __builtin_amdgcn_rcpf(1.f + __expf(-2.f * x)) - 1.f;
}
__device__ __forceinline__ float sel4(f32x4 v, int i) {
  float a = (i & 1) ? v[1] : v[0];
  float b = (i & 1) ? v[3] : v[2];
  return (i & 2) ? b : a;
}
__device__ __forceinline__ float pick(int m, float o0, float o1, float o2, float o3) {
  float a = (m & 1) ? o1 : o0;
  float b = (m & 1) ? o3 : o2;
  return (m & 2) ? b : a;
}

// --- agent-scope (cross-XCD coherent) access helpers ---
__device__ __forceinline__ float agent_ldf(const float* p) {
  return __hip_atomic_load(p, __ATOMIC_RELAXED, __HIP_MEMORY_SCOPE_AGENT);
}
__device__ __forceinline__ void agent_stf(float* p, float v) {
  __hip_atomic_store(p, v, __ATOMIC_RELAXED, __HIP_MEMORY_SCOPE_AGENT);
}
__device__ __forceinline__ u64 agent_ld64(const void* p) {
  return __hip_atomic_load((const u64*)p, __ATOMIC_RELAXED,
                           __HIP_MEMORY_SCOPE_AGENT);
}
__device__ __forceinline__ unsigned int agent_ld32(const void* p) {
  return __hip_atomic_load((const unsigned int*)p, __ATOMIC_RELAXED,
                           __HIP_MEMORY_SCOPE_AGENT);
}
__device__ __forceinline__ void agent_st64(void* p, u64 v) {
  __hip_atomic_store((u64*)p, v, __ATOMIC_RELAXED, __HIP_MEMORY_SCOPE_AGENT);
}
__device__ __forceinline__ void agent_st32(void* p, unsigned int v) {
  __hip_atomic_store((unsigned int*)p, v, __ATOMIC_RELAXED,
                     __HIP_MEMORY_SCOPE_AGENT);
}
__device__ __forceinline__ U16B agent_ld16B(const void* p) {
  U16B r;
  r.lo = agent_ld64(p);
  r.hi = agent_ld64((const char*)p + 8);
  return r;
}
__device__ __forceinline__ void agent_st16x8(void* p, bf16x8 v) {
  U16B u = __builtin_bit_cast(U16B, v);
  agent_st64(p, u.lo);
  agent_st64((char*)p + 8, u.hi);
}

struct SP {
  const unsigned short* Wp;        // [224 ntg][64 kg][16 nn][8 j]: gates|wk|wv|wq
  unsigned short* A0; unsigned short* A1;   // [4224][512] bf16
  __bf16* Zb0; __bf16* Zb1;        // [4096][1024] bf16: k|v bias-folded
  float* q0; float* q1;            // [512] fp32 q bias-folded
  __bf16* coB;                     // [4224][512] bf16 cell state
  float* ht;                       // [65][512]
  const float* biasz;              // [1536] bk|bv|bq
  const float4* bs4; const float4* w04; const float4* w14;
  const float* others; const float* target;
  const float* scene; const float* out_w; const float* out_b;
  float* part; unsigned int* cnt;
  unsigned int* bar;               // tree barrier: see gridbar2
  float* out;
};

// ---------------------------------------------------------------------------
// Fence-free 2-level tree barrier + watchdog.
// bar layout (u32 idx): grpCnt[g]=bar[g*64], rootCnt=bar[512],
// grpGen[g]=bar[(9+g)*64]. Groups by blockIdx>>6: 7 groups of 64 + 1 of 10.
// Data visibility carried by agent-scope stores drained by the vmcnt(0)
// each wave executes before arriving. Watchdog: bail after 2e7 ticks
// (legit waits are <1ms; a deadlock becomes a bounded-time wrong answer).
// ---------------------------------------------------------------------------
__device__ __forceinline__ void gridbar2(unsigned int* bar, unsigned int g) {
  asm volatile("s_waitcnt vmcnt(0) lgkmcnt(0)" ::: "memory");
  __syncthreads();
  if (threadIdx.x == 0) {
    const int gid = blockIdx.x >> 6;
    const unsigned int gsz = (gid == 7) ? 10u : 64u;
    unsigned int* gcnt = bar + gid * 64;
    unsigned int* rcnt = bar + 512;
    unsigned int* ggen = bar + (9 + gid) * 64;
    unsigned int old = atomicAdd(gcnt, 1u);
    if (old == gsz - 1u) {
      atomicExch(gcnt, 0u);                      // reset group counter
      asm volatile("s_waitcnt vmcnt(0)" ::: "memory");
      unsigned int rold = atomicAdd(rcnt, 1u);
      if (rold == 7u) {
        atomicExch(rcnt, 0u);
        asm volatile("s_waitcnt vmcnt(0)" ::: "memory");
#pragma unroll
        for (int gg = 0; gg < 8; ++gg)
          agent_st32(bar + (9 + gg) * 64, g);    // publish generation
      }
    }
    long long t0 = clock64();
    while (__hip_atomic_load(ggen, __ATOMIC_RELAXED,
                             __HIP_MEMORY_SCOPE_AGENT) < g) {
      __builtin_amdgcn_s_sleep(2);
      if (clock64() - t0 > 20000000LL) break;    // watchdog
    }
  }
  __syncthreads();
}

// ---------------------------------------------------------------------------
// One 128x256 GEMM tile for step p + fused epilogue. BK=128.
// A staging: register-staged agent loads + ds_write (double-buffered; next
// K-block's loads issue right after the LDS write barrier and land under
// the MFMA phase). LDS layout: granule g of row r holds k-granule
// (g ^ (r & 15)) (16B granules, 8 bf16).
// ---------------------------------------------------------------------------
__device__ void do_gemm(const SP& P, int p, int bm, int bn)
{
  __shared__ __align__(16) char aLds[2][128 * 128 * 2];   // 2 x 32 KB

  const int tid = threadIdx.x, wave = tid >> 6, lane = tid & 63;
  const unsigned short* A = (p & 1) ? P.A1 : P.A0;
  __bf16* An = (__bf16*)((p & 1) ? P.A0 : P.A1);
  __bf16* Zb = (p & 1) ? P.Zb1 : P.Zb0;
  float* qv  = (p & 1) ? P.q1 : P.q0;
  const int tin = (p + 1 < 31) ? (p + 1) : 31;
  const int tc  = (p + 1 < 63) ? (p + 1) : 63;
  const float* op = P.others + (size_t)tin * 8192;
  const float* tp = P.target + tc * 2;
  float* htn = P.ht + (size_t)(p + 1) * 512;

  const int m0 = bm * 128;
  const int l15 = lane & 15, lq = lane >> 4;

  // A staging: 32 chunks of 1KB per 128-wide K-iter; wave stages 8 chunks.
  int aRow[8], aOff[8], ldsDst[8];
#pragma unroll
  for (int j = 0; j < 8; ++j) {
    int chunk = j * 4 + wave;                 // 0..31
    int r = chunk * 4 + (lane >> 4);          // row local 0..127
    int ch = lane & 15;                       // LDS granule slot
    aRow[j]   = m0 + r;
    aOff[j]   = (ch ^ (r & 15)) * 8;          // global elem offset in row
    ldsDst[j] = chunk * 1024 + lane * 16;     // byte dest in LDS buffer
  }
  const unsigned short* bBase =
      P.Wp + (size_t)(bn * 16 + wave * 4) * 8192 + lq * 128 + l15 * 8;

  f32x4 acc[8][4];
#pragma unroll
  for (int i = 0; i < 8; ++i)
#pragma unroll
    for (int j = 0; j < 4; ++j) acc[i][j] = f32x4{0.f, 0.f, 0.f, 0.f};

  bf16x8 bCur[4], bNext[4];

  U16B rA[8];
#pragma unroll
  for (int j = 0; j < 8; ++j)
    rA[j] = agent_ld16B(A + (size_t)aRow[j] * KD + aOff[j]);
#pragma unroll
  for (int nt = 0; nt < 4; ++nt)
    bCur[nt] = *(const bf16x8*)(bBase + nt * 8192);     // kc = 0

  for (int it = 0; it < 4; ++it) {
    char* wb = aLds[it & 1];
#pragma unroll
    for (int j = 0; j < 8; ++j)
      *(U16B*)(wb + ldsDst[j]) = rA[j];
    __syncthreads();
    if (it < 3) {
      const int k1 = (it + 1) * 128;
#pragma unroll
      for (int j = 0; j < 8; ++j)
        rA[j] = agent_ld16B(A + (size_t)aRow[j] * KD + k1 + aOff[j]);
    }
    const char* buf = aLds[it & 1];
#pragma unroll
    for (int c = 0; c < 4; ++c) {
      const bool hasNext = !(it == 3 && c == 3);
      if (hasNext) {
        const int nkc = it * 4 + c + 1;       // next K-chunk (K=32 units)
#pragma unroll
        for (int nt = 0; nt < 4; ++nt)
          bNext[nt] = *(const bf16x8*)(bBase + nt * 8192 + nkc * 512);
      }
      bf16x8 af[8];
#pragma unroll
      for (int mt = 0; mt < 8; ++mt) {
        int row = mt * 16 + l15;
        int g = (c * 4 + lq) ^ (row & 15);
        af[mt] = *(const bf16x8*)(buf + row * 256 + g * 16);
      }
#pragma unroll
      for (int mt = 0; mt < 8; ++mt)
#pragma unroll
        for (int nt = 0; nt < 4; ++nt)
          acc[mt][nt] = __builtin_amdgcn_mfma_f32_16x16x32_bf16(
              af[mt], bCur[nt], acc[mt][nt], 0, 0, 0);
      if (hasNext) {
#pragma unroll
        for (int nt = 0; nt < 4; ++nt) bCur[nt] = bNext[nt];
      }
    }
  }
  __syncthreads();
  // K-loop done; aLds free for epilogue staging.

  const int rq = lq * 4;

  if (bn >= 12) {
    // ---- q epilogue: row 4096 only (bm==32 tiles) ----
    if (lq == 0) {
#pragma unroll
      for (int nt = 0; nt < 4; ++nt) {
        int qcol = (bn - 12) * 256 + wave * 64 + nt * 16 + l15;
        agent_stf(&qv[qcol], acc[0][nt][0] + P.biasz[1024 + qcol]);
      }
    }
    return;
  }

  if (bn >= 8) {
    // ---- k/v epilogue: LDS transpose -> coalesced agent stores, 2 halves ----
    __bf16* zT = (__bf16*)aLds;          // [64][256] per half (32 KB)
    const int zbase = (bn - 8) * 256;
    float bias[4];
#pragma unroll
    for (int nt = 0; nt < 4; ++nt)
      bias[nt] = P.biasz[zbase + wave * 64 + nt * 16 + l15];
#pragma unroll
    for (int half = 0; half < 2; ++half) {
#pragma unroll
      for (int mt2 = 0; mt2 < 4; ++mt2) {
        int mt = half * 4 + mt2;
#pragma unroll
        for (int nt = 0; nt < 4; ++nt) {
          int ulocal = wave * 64 + nt * 16 + l15;
#pragma unroll
          for (int r = 0; r < 4; ++r) {
            int rloc = mt2 * 16 + rq + r;
            zT[rloc * 256 + ulocal] = (__bf16)(acc[mt][nt][r] + bias[nt]);
          }
        }
      }
      __syncthreads();
      const bf16x8* zc = (const bf16x8*)zT;
#pragma unroll
      for (int i = 0; i < 8; ++i) {
        int idx = i * 256 + tid;
        int rloc = idx >> 5, c8 = idx & 31;
        agent_st16x8(Zb + (size_t)(m0 + half * 64 + rloc) * 1024 + zbase + c8 * 8,
                     zc[idx]);
      }
      __syncthreads();
    }
    return;
  }

  // ---- gate epilogue: fused LSTM cell (R13 form) ----
  const int rho = lane & 3, usel = (lane >> 2) & 3;
  const int u0 = bn * 64 + wave * 16;
  float4 bsv[4], w0v[4], w1v[4];
  int uu[4];
#pragma unroll
  for (int nt = 0; nt < 4; ++nt) {
    uu[nt]  = u0 + nt * 4 + usel;
    bsv[nt] = P.bs4[uu[nt]];
    w0v[nt] = P.w04[uu[nt]];
    w1v[nt] = P.w14[uu[nt]];
  }

  if (bm < 32) {
    __bf16* hT = (__bf16*)aLds[0];       // [128][64]
    __bf16* cT = (__bf16*)aLds[1];       // [128][64]
#pragma unroll
    for (int mt = 0; mt < 8; ++mt) {
      int rloc = mt * 16 + rq + rho;
      int row  = m0 + rloc;
      float x0 = op[2 * row], x1 = op[2 * row + 1];
#pragma unroll
      for (int nt = 0; nt < 4; ++nt) {
        f32x4 v = acc[mt][nt];
        float own = sel4(v, rho);
        float r1  = __shfl_xor(sel4(v, rho ^ 1), 1, 64);
        float r2  = __shfl_xor(sel4(v, rho ^ 2), 2, 64);
        float r3  = __shfl_xor(sel4(v, rho ^ 3), 3, 64);
        float g0 = pick(rho,     own, r1, r2, r3);
        float g1 = pick(rho ^ 1, own, r1, r2, r3);
        float g2 = pick(rho ^ 2, own, r1, r2, r3);
        float g3 = pick(rho ^ 3, own, r1, r2, r3);
        float4 bs = bsv[nt], w0 = w0v[nt], w1 = w1v[nt];
        float p0 = g0 + bs.x + w0.x * x0 + w1.x * x1;
        float p1 = g1 + bs.y + w0.y * x0 + w1.y * x1;
        float p2 = g2 + bs.z + w0.z * x0 + w1.z * x1;
        float p3 = g3 + bs.w + w0.w * x0 + w1.w * x1;
        int u = uu[nt];
        size_t ci = (size_t)row * 512 + u;
        float c_old = (float)P.coB[ci];
        float ii = sigm(p0), ff = sigm(p1), gg = tanh_f(p2), oo = sigm(p3);
        float cn = ff * c_old + ii * gg;
        float h  = oo * tanh_f(cn);
        int ulocal = u - bn * 64;
        hT[rloc * 64 + ulocal] = (__bf16)h;
        cT[rloc * 64 + ulocal] = (__bf16)cn;
      }
    }
    __syncthreads();
    const bf16x8* hc = (const bf16x8*)hT;
    const bf16x8* cc = (const bf16x8*)cT;
#pragma unroll
    for (int i = 0; i < 4; ++i) {
      int idx = i * 256 + tid;
      int rloc = idx >> 3, c8 = idx & 7;
      size_t base = (size_t)(m0 + rloc) * 512 + bn * 64 + c8 * 8;
      agent_st16x8(An + base, hc[idx]);       // cross-block next step
      *(bf16x8*)(P.coB + base) = cc[idx];     // self-read next step: plain
    }
    return;
  }

  // bm == 32: only row 4096 valid. Row-4096 h staged in LDS -> 32x4B agent
  // stores (cross-block next step); coB self-read stays plain.
  unsigned short* hrow = (unsigned short*)aLds;   // 64 entries, cols bn*64..+64
#pragma unroll
  for (int mt = 0; mt < 8; ++mt) {
    int row = m0 + mt * 16 + rq + rho;
    bool act = row <= 4096;
    float x0 = 0.f, x1 = 0.f;
    if (act) { x0 = tp[0]; x1 = tp[1]; }      // act => row == 4096 (m0 = 4096)
#pragma unroll
    for (int nt = 0; nt < 4; ++nt) {
      f32x4 v = acc[mt][nt];
      float own = sel4(v, rho);
      float r1  = __shfl_xor(sel4(v, rho ^ 1), 1, 64);
      float r2  = __shfl_xor(sel4(v, rho ^ 2), 2, 64);
      float r3  = __shfl_xor(sel4(v, rho ^ 3), 3, 64);
      float g0 = pick(rho,     own, r1, r2, r3);
      float g1 = pick(rho ^ 1, own, r1, r2, r3);
      float g2 = pick(rho ^ 2, own, r1, r2, r3);
      float g3 = pick(rho ^ 3, own, r1, r2, r3);
      if (act) {
        float4 bs = bsv[nt], w0 = w0v[nt], w1 = w1v[nt];
        float p0 = g0 + bs.x + w0.x * x0 + w1.x * x1;
        float p1 = g1 + bs.y + w0.y * x0 + w1.y * x1;
        float p2 = g2 + bs.z + w0.z * x0 + w1.z * x1;
        float p3 = g3 + bs.w + w0.w * x0 + w1.w * x1;
        int u = uu[nt];
        size_t ci = (size_t)row * 512 + u;
        float c_old = (float)P.coB[ci];
        float ii = sigm(p0), ff = sigm(p1), gg = tanh_f(p2), oo = sigm(p3);
        float cn = ff * c_old + ii * gg;
        float h  = oo * tanh_f(cn);
        P.coB[ci] = (__bf16)cn;               // self-read next step: plain
        __bf16 hb = (__bf16)h;
        hrow[u - bn * 64] = __builtin_bit_cast(unsigned short, hb);
        agent_stf(htn + u, h);                // cross-block (att finalize)
      }
    }
  }
  __syncthreads();
  if (tid < 32) {
    unsigned int hv = ((const unsigned int*)hrow)[tid];
    agent_st32((unsigned int*)((unsigned short*)An + (size_t)4096 * 512 + bn * 64) + tid,
               hv);
  }
}

// ---------------------------------------------------------------------------
// Attention for step p, task b (64 tasks x 64 rows) + last-done finalize.
// All Zb/q/ht/part traffic agent-scope. Arithmetic bit-identical to R13:
// same per-column add order; thread->column mapping renamed only.
// ---------------------------------------------------------------------------
__device__ void do_att(const SP& P, int p, int b)
{
  __shared__ __align__(16) float qs[512];
  __shared__ float red[256];
  __shared__ float red2[256];
  __shared__ float es[64];
  __shared__ unsigned int sOld;
  const int t = threadIdx.x;
  const __bf16* Zb = (p & 1) ? P.Zb1 : P.Zb0;
  const float* qv  = (p & 1) ? P.q1 : P.q0;
  const float* ht  = P.ht + (size_t)p * 512;

  for (int c = t; c < 512; c += 256) qs[c] = agent_ldf(qv + c);
  __syncthreads();

  const int r0 = b * 64, rl = t >> 2, p4 = t & 3;
  const u64* kr = (const u64*)(Zb + (size_t)(r0 + rl) * 1024);
  float a = 0.f;
  for (int i = p4; i < 64; i += 4) {
    U16B tmp;
    tmp.lo = agent_ld64(kr + 2 * i);
    tmp.hi = agent_ld64(kr + 2 * i + 1);
    bf16x8 kk = __builtin_bit_cast(bf16x8, tmp);
    const float* qq = qs + i * 8;
#pragma unroll
    for (int j = 0; j < 8; ++j) a += (float)kk[j] * qq[j];
  }
  red[t] = a;
  __syncthreads();
  if (t < 64)
    es[t] = __expf((red[4 * t] + red[4 * t + 1] + red[4 * t + 2] + red[4 * t + 3]) *
                   0.04419417382415922f);
  __syncthreads();

  // V pass: thread t owns columns 2t, 2t+1 (same per-column add order as R13).
  float s0 = 0.f, s1 = 0.f;
  for (int r = 0; r < 64; ++r) {
    const unsigned int* vr =
        (const unsigned int*)(Zb + (size_t)(r0 + r) * 1024 + 512);
    unsigned int wv = agent_ld32(vr + t);
    float e = es[r];
    __bf16 v0 = __builtin_bit_cast(__bf16, (unsigned short)(wv & 0xffffu));
    __bf16 v1 = __builtin_bit_cast(__bf16, (unsigned short)(wv >> 16));
    s0 += e * (float)v0;
    s1 += e * (float)v1;
  }
  agent_stf(&P.part[b * 513 + 2 * t],     s0);
  agent_stf(&P.part[b * 513 + 2 * t + 1], s1);
  if (t == 0) {
    float se = 0.f;
#pragma unroll
    for (int r = 0; r < 64; ++r) se += es[r];
    agent_stf(&P.part[b * 513 + 512], se);
  }
  asm volatile("s_waitcnt vmcnt(0) lgkmcnt(0)" ::: "memory");
  __syncthreads();
  if (t == 0) sOld = atomicAdd(P.cnt, 1u);
  __syncthreads();
  if (sOld == 63) {
    float s = 0.f, s2 = 0.f, se = 0.f;
    for (int bb = 0; bb < 64; ++bb) {
      s  += agent_ldf(&P.part[bb * 513 + t]);
      s2 += agent_ldf(&P.part[bb * 513 + 256 + t]);
      se += agent_ldf(&P.part[bb * 513 + 512]);
    }
    float inv = 1.f / se;
    float va = agent_ldf(&ht[t])       + s  * inv + P.scene[t];
    float vb = agent_ldf(&ht[t + 256]) + s2 * inv + P.scene[t + 256];
    red[t]  = va * P.out_w[t]       + vb * P.out_w[t + 256];
    red2[t] = va * P.out_w[512 + t] + vb * P.out_w[768 + t];
    __syncthreads();
    for (int st = 128; st > 0; st >>= 1) {
      if (t < st) { red[t] += red[t + st]; red2[t] += red2[t + st]; }
      __syncthreads();
    }
    if (t == 0) {
      P.out[2 * p]     = red[0]  + P.out_b[0];
      P.out[2 * p + 1] = red2[0] + P.out_b[1];
      atomicExch(P.cnt, 0u);
    }
  }
}

// ---------------------------------------------------------------------------
// Persistent kernel: 458 blocks, 64 steps, tree barrier between steps.
// Block role fixed (R16 decode): w = xcd*57 + min(xcd,2) + slot.
// w < 448: bm=w/14, j=w%14; j<12 -> gemm(bm,j); j in {12,13} -> att task
// 2*bm+(j-12) for step p-1. w >= 448: bm=32 tail tiles (gates + q).
// ---------------------------------------------------------------------------
__global__ __launch_bounds__(256, 2) void main_kernel(SP P)
{
  const int xcd  = blockIdx.x & 7;
  const int slot = blockIdx.x >> 3;
  const int w = xcd * 57 + (xcd < 2 ? xcd : 2) + slot;

  int bm = 0, bn = 0, attTask = -1;
  if (w < 448) {
    bm = w / 14;
    int j = w % 14;
    if (j < 12) bn = j;
    else attTask = 2 * bm + (j - 12);
  } else {
    int ti = w - 448;
    bm = 32;
    bn = (ti < 8) ? ti : (12 + (ti - 8));
  }

  for (int p = 0; p < 64; ++p) {
    if (attTask >= 0) {
      if (p >= 1) do_att(P, p - 1, attTask);
    } else {
      do_gemm(P, p, bm, bn);
    }
    gridbar2(P.bar, (unsigned int)(p + 1));
  }
  if (attTask >= 0) do_att(P, 63, attTask);
}

// ---------------------------------------------------------------------------
// Prep kernels (R16 verbatim; init_state also zeroes barrier region).
// ---------------------------------------------------------------------------
__global__ __launch_bounds__(256) void init_state(
    const float* __restrict__ others0, const float* __restrict__ target0,
    const float* __restrict__ w_ih, const float* __restrict__ b_ih,
    const float* __restrict__ b_hh,
    __bf16* __restrict__ coB, __bf16* __restrict__ A0, float* __restrict__ ht0,
    unsigned int* __restrict__ cnt, unsigned int* __restrict__ bar)
{
  int g = blockIdx.x * 256 + threadIdx.x;
  if (g == 0) cnt[0] = 0u;
  if (g < 2048) bar[g] = 0u;
  if (g >= 4097 * 512) return;
  int r = g >> 9, j = g & 511;
  float x0, x1;
  if (r < 4096) { x0 = others0[2 * r]; x1 = others0[2 * r + 1]; }
  else          { x0 = target0[0];     x1 = target0[1]; }
  float pre[4];
#pragma unroll
  for (int gg = 0; gg < 4; ++gg) {
    int n = gg * 512 + j;
    pre[gg] = b_ih[n] + b_hh[n] + w_ih[2 * n] * x0 + w_ih[2 * n + 1] * x1;
  }
  float cn = sigm(pre[0]) * tanh_f(pre[2]);
  float h  = sigm(pre[3]) * tanh_f(cn);
  coB[g] = (__bf16)cn;
  A0[g] = (__bf16)h;
  if (r == 4096) ht0[j] = h;
}

__global__ __launch_bounds__(256) void pack_w(
    const float* __restrict__ w_hh, const float* __restrict__ wk,
    const float* __restrict__ wv,   const float* __restrict__ wq,
    __bf16* __restrict__ Wp)
{
  int o = blockIdx.x * 256 + threadIdx.x;   // 1,835,008
  int j = o & 7, nn = (o >> 3) & 15, kg = (o >> 7) & 63, ntg = o >> 13;
  int n = ntg * 16 + nn, k = kg * 8 + j;
  float v;
  if (n < 2048)      { int u = n >> 2, g = n & 3; v = w_hh[(g * 512 + u) * 512 + k]; }
  else if (n < 2560) v = wk[(n - 2048) * 512 + k];
  else if (n < 3072) v = wv[(n - 2560) * 512 + k];
  else               v = wq[(n - 3072) * 512 + k];
  Wp[o] = (__bf16)v;
}

__global__ __launch_bounds__(256) void pack_misc(
    const float* __restrict__ b_ih, const float* __restrict__ b_hh,
    const float* __restrict__ w_ih,
    const float* __restrict__ bk, const float* __restrict__ bv,
    const float* __restrict__ bq,
    float* __restrict__ bs, float* __restrict__ w0, float* __restrict__ w1,
    float* __restrict__ biasz)
{
  int i = blockIdx.x * 256 + threadIdx.x;
  if (i < 2048) {
    int u = i >> 2, g = i & 3, n = g * 512 + u;
    bs[i] = b_ih[n] + b_hh[n];
    w0[i] = w_ih[2 * n];
    w1[i] = w_ih[2 * n + 1];
  } else if (i < 2048 + 1536) {
    int z = i - 2048;
    biasz[z] = (z < 512) ? bk[z] : (z < 1024 ? bv[z - 512] : bq[z - 1024]);
  }
}

__global__ __launch_bounds__(256) void scene1_kernel(
    const int* __restrict__ map, const float* __restrict__ emb,
    const float* __restrict__ w1, const float* __restrict__ b1,
    float* __restrict__ out1)
{
  __shared__ float wl[576];
  __shared__ float bl[16];
  const int t = threadIdx.x;
  for (int i = t; i < 576; i += 256) wl[i] = w1[i];
  if (t < 16) bl[t] = b1[t];
  __syncthreads();
  const int y = blockIdx.x, x = t;
  float nb[4][9];
#pragma unroll
  for (int dy = 0; dy < 3; ++dy)
#pragma unroll
    for (int dx = 0; dx < 3; ++dx) {
      int yy = y + dy - 1, xx = x + dx - 1;
      bool ok = (yy >= 0 && yy < 256 && xx >= 0 && xx < 256);
      int m = ok ? map[yy * 256 + xx] : 0;
#pragma unroll
      for (int c = 0; c < 4; ++c)
        nb[c][dy * 3 + dx] = ok ? emb[m * 4 + c] : 0.f;
    }
  for (int oc = 0; oc < 16; ++oc) {
    float a = bl[oc];
#pragma unroll
    for (int c = 0; c < 4; ++c)
#pragma unroll
      for (int k = 0; k < 9; ++k) a += wl[(oc * 4 + c) * 9 + k] * nb[c][k];
    out1[oc * 65536 + y * 256 + x] = fmaxf(a, 0.f);
  }
}

__global__ __launch_bounds__(256) void scene2_kernel(
    const float* __restrict__ out1, const float* __restrict__ w2,
    const float* __restrict__ b2, float* __restrict__ rowpart)
{
  __shared__ float wl[1152];
  __shared__ float lds4[4 * 8];
  const int t = threadIdx.x;
  const int y = blockIdx.x & 255, ocg = blockIdx.x >> 8;
  for (int i = t; i < 1152; i += 256) wl[i] = w2[ocg * 1152 + i];
  __syncthreads();
  const int x = t;
  float acc[8];
#pragma unroll
  for (int o = 0; o < 8; ++o) acc[o] = b2[ocg * 8 + o];
  for (int ic = 0; ic < 16; ++ic) {
    float nb[9];
#pragma unroll
    for (int dy = 0; dy < 3; ++dy)
#pragma unroll
      for (int dx = 0; dx < 3; ++dx) {
        int yy = y + dy - 1, xx = x + dx - 1;
        bool ok = (yy >= 0 && yy < 256 && xx >= 0 && xx < 256);
        nb[dy * 3 + dx] = ok ? out1[ic * 65536 + yy * 256 + xx] : 0.f;
      }
#pragma unroll
    for (int o = 0; o < 8; ++o) {
      const float* w = &wl[(o * 16 + ic) * 9];
#pragma unroll
      for (int k = 0; k < 9; ++k) acc[o] += w[k] * nb[k];
    }
  }
  const int wave = t >> 6, lane = t & 63;
#pragma unroll
  for (int o = 0; o < 8; ++o) {
    float v = fmaxf(acc[o], 0.f);
#pragma unroll
    for (int m = 1; m < 64; m <<= 1) v += __shfl_xor(v, m, 64);
    if (lane == 0) lds4[wave * 8 + o] = v;
  }
  __syncthreads();
  if (t < 8)
    rowpart[y * 32 + ocg * 8 + t] = lds4[t] + lds4[8 + t] + lds4[16 + t] + lds4[24 + t];
}

__global__ __launch_bounds__(512) void scene3_kernel(
    const float* __restrict__ rowpart, const float* __restrict__ fcw,
    const float* __restrict__ fcb, float* __restrict__ scene)
{
  __shared__ float mean[32];
  const int t = threadIdx.x;
  if (t < 32) {
    float s = 0.f;
    for (int y = 0; y < 256; ++y) s += rowpart[y * 32 + t];
    mean[t] = s * (1.f / 65536.f);
  }
  __syncthreads();
  float a = fcb[t];
#pragma unroll
  for (int c = 0; c < 32; ++c) a += mean[c] * fcw[t * 32 + c];
  scene[t] = a;
}

// ---------------------------------------------------------------------------
extern "C" void kernel_launch(void* const* d_in, const int* in_sizes, int n_in,
                              void* d_out, int out_size, void* d_ws, size_t ws_size,
                              hipStream_t stream) {
  const float* target    = (const float*)d_in[0];
  const float* others    = (const float*)d_in[1];
  const int*   scene_map = (const int*)d_in[2];
  const float* emb       = (const float*)d_in[3];
  const float* c1w       = (const float*)d_in[4];
  const float* c1b       = (const float*)d_in[5];
  const float* c2w       = (const float*)d_in[6];
  const float* c2b       = (const float*)d_in[7];
  const float* fcw       = (const float*)d_in[8];
  const float* fcb       = (const float*)d_in[9];
  const float* w_ih      = (const float*)d_in[10];
  const float* w_hh      = (const float*)d_in[11];
  const float* b_ih      = (const float*)d_in[12];
  const float* b_hh      = (const float*)d_in[13];
  const float* wq        = (const float*)d_in[14];
  const float* bq        = (const float*)d_in[15];
  const float* wk        = (const float*)d_in[16];
  const float* bk        = (const float*)d_in[17];
  const float* wv        = (const float*)d_in[18];
  const float* bv        = (const float*)d_in[19];
  const float* out_w     = (const float*)d_in[20];
  const float* out_b     = (const float*)d_in[21];
  float* out = (float*)d_out;

  char* ws = (char*)d_ws;
  size_t off = 0;
  auto alloc = [&](size_t bytes) { size_t o = off; off += (bytes + 255) & ~(size_t)255; return o; };
  __bf16* Zb0   = (__bf16*)(ws + alloc((size_t)4096 * 1024 * 2));
  __bf16* Zb1   = (__bf16*)(ws + alloc((size_t)4096 * 1024 * 2));
  float*  q0    = (float*)(ws + alloc(512 * 4));
  float*  q1    = (float*)(ws + alloc(512 * 4));
  __bf16* Wp    = (__bf16*)(ws + alloc((size_t)1835008 * 2));
  __bf16* A0    = (__bf16*)(ws + alloc((size_t)4224 * 512 * 2));
  __bf16* A1    = (__bf16*)(ws + alloc((size_t)4224 * 512 * 2));
  __bf16* coB   = (__bf16*)(ws + alloc((size_t)4224 * 512 * 2));
  float*  ht    = (float*)(ws + alloc((size_t)65 * 512 * 4));
  float*  scene = (float*)(ws + alloc(2048));
  float*  part  = (float*)(ws + alloc(64 * 513 * 4));
  unsigned int* cnt = (unsigned int*)(ws + alloc(256));
  unsigned int* bar = (unsigned int*)(ws + alloc(8192));
  float*  bs    = (float*)(ws + alloc(2048 * 4));
  float*  w0p   = (float*)(ws + alloc(2048 * 4));
  float*  w1p   = (float*)(ws + alloc(2048 * 4));
  float*  biasz = (float*)(ws + alloc(1536 * 4));
  float*  out1  = (float*)(ws + alloc((size_t)16 * 65536 * 4));
  float*  rowp  = (float*)(ws + alloc(256 * 32 * 4));

  pack_w<<<7168, 256, 0, stream>>>(w_hh, wk, wv, wq, Wp);
  pack_misc<<<14, 256, 0, stream>>>(b_ih, b_hh, w_ih, bk, bv, bq, bs, w0p, w1p, biasz);
  scene1_kernel<<<256, 256, 0, stream>>>(scene_map, emb, c1w, c1b, out1);
  scene2_kernel<<<1024, 256, 0, stream>>>(out1, c2w, c2b, rowp);
  scene3_kernel<<<1, 512, 0, stream>>>(rowp, fcw, fcb, scene);
  init_state<<<8194, 256, 0, stream>>>(others, target, w_ih, b_ih, b_hh, coB, A0, ht, cnt, bar);

  SP hp;
  hp.Wp = (const unsigned short*)Wp;
  hp.A0 = (unsigned short*)A0; hp.A1 = (unsigned short*)A1;
  hp.Zb0 = Zb0; hp.Zb1 = Zb1;
  hp.q0 = q0; hp.q1 = q1;
  hp.coB = coB; hp.ht = ht;
  hp.biasz = biasz;
  hp.bs4 = (const float4*)bs; hp.w04 = (const float4*)w0p; hp.w14 = (const float4*)w1p;
  hp.others = others; hp.target = target;
  hp.scene = scene; hp.out_w = out_w; hp.out_b = out_b;
  hp.part = part; hp.cnt = cnt;
  hp.bar = bar;
  hp.out = out;

  main_kernel<<<458, 256, 0, stream>>>(hp);
}

// Round 6
// 2687.764 us; speedup vs baseline: 2.6894x; 1.4271x over previous
//
#include <hip/hip_runtime.h>
#include <hip/hip_bf16.h>

// ---------------------------------------------------------------------------
// Sophie on MI355X, round 21: multi-launch (R16 semantics) + 8-wave blocks.
// R5 post-mortem: persistent kernel abandoned (agent-scope = L2 bypass,
// fences = L2 nuke; both cost more than 64 hardware launches). R5 counters
// showed the step kernel is LATENCY-bound: MfmaUtil 9%, VALUBusy 11%,
// occupancy ~2 waves/SIMD. This round doubles wave-level latency hiding:
// 512-thread GEMM blocks (8 waves x 2 column-groups instead of 4 waves x 4),
// same 128x256 tile, same LDS (64KB -> still 2 blocks/CU -> 14.3 waves/CU
// vs 7.2), same traffic, bit-identical per-accumulator arithmetic.
// launch_bounds(512,4) caps VGPR at 128 to keep 4 waves/SIMD resident.
// do_att runs at 512 threads with work guarded to t<256 (barriers at top
// level; add order identical to R13/R16).
// ---------------------------------------------------------------------------

typedef __bf16 bf16x8 __attribute__((ext_vector_type(8)));
typedef float  f32x4  __attribute__((ext_vector_type(4)));

#define KD 512

__device__ __forceinline__ void gl_lds16(const void* g, void* l) {
  __builtin_amdgcn_global_load_lds(
      (const __attribute__((address_space(1))) void*)g,
      (__attribute__((address_space(3))) void*)l, 16, 0, 0);
}
__device__ __forceinline__ float sigm(float x) {
  return __builtin_amdgcn_rcpf(1.f + __expf(-x));
}
__device__ __forceinline__ float tanh_f(float x) {
  return 2.f * __builtin_amdgcn_rcpf(1.f + __expf(-2.f * x)) - 1.f;
}
__device__ __forceinline__ float sel4(f32x4 v, int i) {
  float a = (i & 1) ? v[1] : v[0];
  float b = (i & 1) ? v[3] : v[2];
  return (i & 2) ? b : a;
}
__device__ __forceinline__ float pick(int m, float o0, float o1, float o2, float o3) {
  float a = (m & 1) ? o1 : o0;
  float b = (m & 1) ? o3 : o2;
  return (m & 2) ? b : a;
}

struct SP {
  const unsigned short* Wp;        // [224 ntg][64 kg][16 nn][8 j]: gates|wk|wv|wq
  unsigned short* A0; unsigned short* A1;   // [4224][512] bf16
  __bf16* Zb0; __bf16* Zb1;        // [4096][1024] bf16: k|v bias-folded
  float* q0; float* q1;            // [512] fp32 q bias-folded
  __bf16* coB;                     // [4224][512] bf16 cell state
  float* ht;                       // [65][512]
  const float* biasz;              // [1536] bk|bv|bq
  const float4* bs4; const float4* w04; const float4* w14;
  const float* others; const float* target;
  const float* scene; const float* out_w; const float* out_b;
  float* part; unsigned int* cnt;
  float* out;
};

// ---------------------------------------------------------------------------
// One 128x256 GEMM tile for step p + fused epilogue. BK=128, 8 waves.
// Wave w owns column-groups ntg = bn*16 + 2w + {0,1} (32 cols).
// LDS layout unchanged: granule g of row r holds k-granule (g ^ (r & 15)).
// A staging: 32 chunks of 1KB; each wave stages 4 (chunk = j*8 + wave).
// ---------------------------------------------------------------------------
__device__ void do_gemm(const SP& P, int p, int bm, int bn)
{
  __shared__ __align__(16) char aLds[2][128 * 128 * 2];   // 2 x 32 KB

  const int tid = threadIdx.x, wave = tid >> 6, lane = tid & 63;
  const unsigned short* A = (p & 1) ? P.A1 : P.A0;
  __bf16* An = (__bf16*)((p & 1) ? P.A0 : P.A1);
  __bf16* Zb = (p & 1) ? P.Zb1 : P.Zb0;
  float* qv  = (p & 1) ? P.q1 : P.q0;
  const int tin = (p + 1 < 31) ? (p + 1) : 31;
  const int tc  = (p + 1 < 63) ? (p + 1) : 63;
  const float* op = P.others + (size_t)tin * 8192;
  const float* tp = P.target + tc * 2;
  float* htn = P.ht + (size_t)(p + 1) * 512;

  const int m0 = bm * 128;
  const int l15 = lane & 15, lq = lane >> 4;

  int aRow[4], aOff[4], ldsOff[4];
#pragma unroll
  for (int j = 0; j < 4; ++j) {
    int chunk = j * 8 + wave;                 // 0..31
    int r = chunk * 4 + (lane >> 4);          // row local 0..127
    int ch = lane & 15;                       // LDS granule slot
    aRow[j]   = m0 + r;
    aOff[j]   = (ch ^ (r & 15)) * 8;          // global elem offset in row
    ldsOff[j] = chunk * 1024;
  }
  const unsigned short* bBase =
      P.Wp + (size_t)(bn * 16 + wave * 2) * 8192 + lq * 128 + l15 * 8;

  f32x4 acc[8][2];
#pragma unroll
  for (int i = 0; i < 8; ++i)
#pragma unroll
    for (int j = 0; j < 2; ++j) acc[i][j] = f32x4{0.f, 0.f, 0.f, 0.f};

  bf16x8 bCur[2], bNext[2];

#pragma unroll
  for (int j = 0; j < 4; ++j)
    gl_lds16(A + (size_t)aRow[j] * KD + aOff[j], aLds[0] + ldsOff[j]);
#pragma unroll
  for (int nt = 0; nt < 2; ++nt)
    bCur[nt] = *(const bf16x8*)(bBase + nt * 8192);     // kc = 0
  __syncthreads();

  for (int it = 0; it < 4; ++it) {
    if (it < 3) {
      const int k1 = (it + 1) * 128;
#pragma unroll
      for (int j = 0; j < 4; ++j)
        gl_lds16(A + (size_t)aRow[j] * KD + k1 + aOff[j],
                 aLds[(it + 1) & 1] + ldsOff[j]);
    }
    const char* buf = aLds[it & 1];
#pragma unroll
    for (int c = 0; c < 4; ++c) {
      const bool hasNext = !(it == 3 && c == 3);
      if (hasNext) {
        const int nkc = it * 4 + c + 1;       // next K-chunk (K=32 units)
#pragma unroll
        for (int nt = 0; nt < 2; ++nt)
          bNext[nt] = *(const bf16x8*)(bBase + nt * 8192 + nkc * 512);
      }
      // two half-batches of A fragments (reduces register pressure)
#pragma unroll
      for (int mh = 0; mh < 2; ++mh) {
        bf16x8 af[4];
#pragma unroll
        for (int m4 = 0; m4 < 4; ++m4) {
          int row = (mh * 4 + m4) * 16 + l15;
          int g = (c * 4 + lq) ^ (row & 15);
          af[m4] = *(const bf16x8*)(buf + row * 256 + g * 16);
        }
#pragma unroll
        for (int m4 = 0; m4 < 4; ++m4)
#pragma unroll
          for (int nt = 0; nt < 2; ++nt)
            acc[mh * 4 + m4][nt] = __builtin_amdgcn_mfma_f32_16x16x32_bf16(
                af[m4], bCur[nt], acc[mh * 4 + m4][nt], 0, 0, 0);
      }
      if (hasNext) {
#pragma unroll
        for (int nt = 0; nt < 2; ++nt) bCur[nt] = bNext[nt];
      }
    }
    __syncthreads();
  }
  // K-loop done; aLds free for epilogue staging.

  const int rq = lq * 4;

  if (bn >= 12) {
    // ---- q epilogue: row 4096 only (bm==32 tiles) ----
    if (lq == 0) {
#pragma unroll
      for (int nt = 0; nt < 2; ++nt) {
        int qcol = (bn - 12) * 256 + wave * 32 + nt * 16 + l15;
        qv[qcol] = acc[0][nt][0] + P.biasz[1024 + qcol];
      }
    }
    return;
  }

  if (bn >= 8) {
    // ---- k/v epilogue: LDS transpose -> coalesced 16B stores, 2 halves ----
    __bf16* zT = (__bf16*)aLds;          // [64][256] per half (32 KB)
    const int zbase = (bn - 8) * 256;
    float bias[2];
#pragma unroll
    for (int nt = 0; nt < 2; ++nt)
      bias[nt] = P.biasz[zbase + wave * 32 + nt * 16 + l15];
#pragma unroll
    for (int half = 0; half < 2; ++half) {
#pragma unroll
      for (int mt2 = 0; mt2 < 4; ++mt2) {
        int mt = half * 4 + mt2;
#pragma unroll
        for (int nt = 0; nt < 2; ++nt) {
          int ulocal = wave * 32 + nt * 16 + l15;
#pragma unroll
          for (int r = 0; r < 4; ++r) {
            int rloc = mt2 * 16 + rq + r;
            zT[rloc * 256 + ulocal] = (__bf16)(acc[mt][nt][r] + bias[nt]);
          }
        }
      }
      __syncthreads();
      const bf16x8* zc = (const bf16x8*)zT;
#pragma unroll
      for (int i = 0; i < 4; ++i) {
        int idx = i * 512 + tid;
        int rloc = idx >> 5, c8 = idx & 31;
        *(bf16x8*)(Zb + (size_t)(m0 + half * 64 + rloc) * 1024 + zbase + c8 * 8) = zc[idx];
      }
      __syncthreads();
    }
    return;
  }

  // ---- gate epilogue: fused LSTM cell (R13 form; 8 u-cols per wave) ----
  const int rho = lane & 3, usel = (lane >> 2) & 3;
  const int u0 = bn * 64 + wave * 8;
  float4 bsv[2], w0v[2], w1v[2];
  int uu[2];
#pragma unroll
  for (int nt = 0; nt < 2; ++nt) {
    uu[nt]  = u0 + nt * 4 + usel;
    bsv[nt] = P.bs4[uu[nt]];
    w0v[nt] = P.w04[uu[nt]];
    w1v[nt] = P.w14[uu[nt]];
  }

  if (bm < 32) {
    __bf16* hT = (__bf16*)aLds[0];       // [128][64]
    __bf16* cT = (__bf16*)aLds[1];       // [128][64]
#pragma unroll
    for (int mt = 0; mt < 8; ++mt) {
      int rloc = mt * 16 + rq + rho;
      int row  = m0 + rloc;
      float x0 = op[2 * row], x1 = op[2 * row + 1];
#pragma unroll
      for (int nt = 0; nt < 2; ++nt) {
        f32x4 v = acc[mt][nt];
        float own = sel4(v, rho);
        float r1  = __shfl_xor(sel4(v, rho ^ 1), 1, 64);
        float r2  = __shfl_xor(sel4(v, rho ^ 2), 2, 64);
        float r3  = __shfl_xor(sel4(v, rho ^ 3), 3, 64);
        float g0 = pick(rho,     own, r1, r2, r3);
        float g1 = pick(rho ^ 1, own, r1, r2, r3);
        float g2 = pick(rho ^ 2, own, r1, r2, r3);
        float g3 = pick(rho ^ 3, own, r1, r2, r3);
        float4 bs = bsv[nt], w0 = w0v[nt], w1 = w1v[nt];
        float p0 = g0 + bs.x + w0.x * x0 + w1.x * x1;
        float p1 = g1 + bs.y + w0.y * x0 + w1.y * x1;
        float p2 = g2 + bs.z + w0.z * x0 + w1.z * x1;
        float p3 = g3 + bs.w + w0.w * x0 + w1.w * x1;
        int u = uu[nt];
        size_t ci = (size_t)row * 512 + u;
        float c_old = (float)P.coB[ci];
        float ii = sigm(p0), ff = sigm(p1), gg = tanh_f(p2), oo = sigm(p3);
        float cn = ff * c_old + ii * gg;
        float h  = oo * tanh_f(cn);
        int ulocal = u - bn * 64;
        hT[rloc * 64 + ulocal] = (__bf16)h;
        cT[rloc * 64 + ulocal] = (__bf16)cn;
      }
    }
    __syncthreads();
    const bf16x8* hc = (const bf16x8*)hT;
    const bf16x8* cc = (const bf16x8*)cT;
#pragma unroll
    for (int i = 0; i < 2; ++i) {
      int idx = i * 512 + tid;
      int rloc = idx >> 3, c8 = idx & 7;
      size_t base = (size_t)(m0 + rloc) * 512 + bn * 64 + c8 * 8;
      *(bf16x8*)(An + base)    = hc[idx];
      *(bf16x8*)(P.coB + base) = cc[idx];
    }
    return;
  }

  // bm == 32: only row 4096 valid
#pragma unroll
  for (int mt = 0; mt < 8; ++mt) {
    int row = m0 + mt * 16 + rq + rho;
    bool act = row <= 4096;
    float x0 = 0.f, x1 = 0.f;
    if (act) {
      if (row < 4096) { x0 = op[2 * row]; x1 = op[2 * row + 1]; }
      else            { x0 = tp[0];       x1 = tp[1]; }
    }
#pragma unroll
    for (int nt = 0; nt < 2; ++nt) {
      f32x4 v = acc[mt][nt];
      float own = sel4(v, rho);
      float r1  = __shfl_xor(sel4(v, rho ^ 1), 1, 64);
      float r2  = __shfl_xor(sel4(v, rho ^ 2), 2, 64);
      float r3  = __shfl_xor(sel4(v, rho ^ 3), 3, 64);
      float g0 = pick(rho,     own, r1, r2, r3);
      float g1 = pick(rho ^ 1, own, r1, r2, r3);
      float g2 = pick(rho ^ 2, own, r1, r2, r3);
      float g3 = pick(rho ^ 3, own, r1, r2, r3);
      if (act) {
        float4 bs = bsv[nt], w0 = w0v[nt], w1 = w1v[nt];
        float p0 = g0 + bs.x + w0.x * x0 + w1.x * x1;
        float p1 = g1 + bs.y + w0.y * x0 + w1.y * x1;
        float p2 = g2 + bs.z + w0.z * x0 + w1.z * x1;
        float p3 = g3 + bs.w + w0.w * x0 + w1.w * x1;
        int u = uu[nt];
        size_t ci = (size_t)row * 512 + u;
        float c_old = (float)P.coB[ci];
        float ii = sigm(p0), ff = sigm(p1), gg = tanh_f(p2), oo = sigm(p3);
        float cn = ff * c_old + ii * gg;
        float h  = oo * tanh_f(cn);
        P.coB[ci] = (__bf16)cn;
        An[ci] = (__bf16)h;
        if (row == 4096) htn[u] = h;
      }
    }
  }
}

// ---------------------------------------------------------------------------
// Attention for step p, task b + last-done finalize. 512 threads; all
// barriers at top level, work guarded to t<256. Arithmetic identical to R16.
// ---------------------------------------------------------------------------
__device__ void do_att(const SP& P, int p, int b)
{
  __shared__ __align__(16) float qs[512];
  __shared__ float red[256];
  __shared__ float red2[256];
  __shared__ float es[64];
  __shared__ unsigned int sOld;
  const int t = threadIdx.x;
  const __bf16* Zb = (p & 1) ? P.Zb1 : P.Zb0;
  const float* qv  = (p & 1) ? P.q1 : P.q0;
  const float* ht  = P.ht + (size_t)p * 512;

  qs[t] = qv[t];                       // blockDim == 512
  __syncthreads();

  const int r0 = b * 64;
  if (t < 256) {
    const int rl = t >> 2, p4 = t & 3;
    const bf16x8* krow = (const bf16x8*)(Zb + (size_t)(r0 + rl) * 1024);
    float a = 0.f;
    for (int i = p4; i < 64; i += 4) {
      bf16x8 kk = krow[i];
      const float* qq = qs + i * 8;
#pragma unroll
      for (int j = 0; j < 8; ++j) a += (float)kk[j] * qq[j];
    }
    red[t] = a;
  }
  __syncthreads();
  if (t < 64)
    es[t] = __expf((red[4 * t] + red[4 * t + 1] + red[4 * t + 2] + red[4 * t + 3]) *
                   0.04419417382415922f);
  __syncthreads();

  if (t < 256) {
    float s0 = 0.f, s1 = 0.f;
    for (int r = 0; r < 64; ++r) {
      const __bf16* vr = Zb + (size_t)(r0 + r) * 1024 + 512;
      float e = es[r];
      s0 += e * (float)vr[t];
      s1 += e * (float)vr[t + 256];
    }
    P.part[b * 513 + t] = s0;
    P.part[b * 513 + 256 + t] = s1;
    if (t == 0) {
      float se = 0.f;
#pragma unroll
      for (int r = 0; r < 64; ++r) se += es[r];
      P.part[b * 513 + 512] = se;
    }
  }
  __threadfence();
  __syncthreads();
  if (t == 0) sOld = atomicAdd(P.cnt, 1u);
  __syncthreads();
  if (sOld == 63) {
    __threadfence();
    if (t < 256) {
      float s = 0.f, s2 = 0.f, se = 0.f;
      for (int bb = 0; bb < 64; ++bb) {
        s  += P.part[bb * 513 + t];
        s2 += P.part[bb * 513 + 256 + t];
        se += P.part[bb * 513 + 512];
      }
      float inv = 1.f / se;
      float va = ht[t] + s * inv + P.scene[t];
      float vb = ht[t + 256] + s2 * inv + P.scene[t + 256];
      red[t]  = va * P.out_w[t]       + vb * P.out_w[t + 256];
      red2[t] = va * P.out_w[512 + t] + vb * P.out_w[768 + t];
    }
    __syncthreads();
    for (int st = 128; st > 0; st >>= 1) {
      if (t < st) { red[t] += red[t + st]; red2[t] += red2[t + st]; }
      __syncthreads();
    }
    if (t == 0) {
      P.out[2 * p]     = red[0]  + P.out_b[0];
      P.out[2 * p + 1] = red2[0] + P.out_b[1];
      *P.cnt = 0;
    }
  }
}

// ---------------------------------------------------------------------------
// Step dispatch: 458 blocks x 512 threads (R16 decode).
// w = xcd*57 + min(xcd,2) + slot (bijective over [0,458)).
// w < 448: bm = w/14, j = w%14; j<12 -> gemm(bm,j); j in {12,13} -> att
// task 2*bm+(j-12) for step p-1. w >= 448: bm=32 tail tiles (gates + q).
// ---------------------------------------------------------------------------
__global__ __launch_bounds__(512, 4) void step_kernel(SP P, int p)
{
  const int xcd  = blockIdx.x & 7;
  const int slot = blockIdx.x >> 3;
  const int w = xcd * 57 + (xcd < 2 ? xcd : 2) + slot;
  if (w < 448) {
    int bm = w / 14, j = w % 14;
    if (j < 12) {
      do_gemm(P, p, bm, j);
    } else {
      if (p >= 1) do_att(P, p - 1, 2 * bm + (j - 12));
    }
  } else {
    int ti = w - 448;
    int bn = (ti < 8) ? ti : (12 + (ti - 8));
    do_gemm(P, p, 32, bn);
  }
}

__global__ __launch_bounds__(512) void att_step(SP P, int p) {
  do_att(P, p, blockIdx.x);
}

// ---------------------------------------------------------------------------
// Prep kernels (R16 verbatim).
// ---------------------------------------------------------------------------
__global__ __launch_bounds__(256) void init_state(
    const float* __restrict__ others0, const float* __restrict__ target0,
    const float* __restrict__ w_ih, const float* __restrict__ b_ih,
    const float* __restrict__ b_hh,
    __bf16* __restrict__ coB, __bf16* __restrict__ A0, float* __restrict__ ht0,
    unsigned int* __restrict__ cnt)
{
  int g = blockIdx.x * 256 + threadIdx.x;
  if (g == 0) *cnt = 0u;
  if (g >= 4097 * 512) return;
  int r = g >> 9, j = g & 511;
  float x0, x1;
  if (r < 4096) { x0 = others0[2 * r]; x1 = others0[2 * r + 1]; }
  else          { x0 = target0[0];     x1 = target0[1]; }
  float pre[4];
#pragma unroll
  for (int gg = 0; gg < 4; ++gg) {
    int n = gg * 512 + j;
    pre[gg] = b_ih[n] + b_hh[n] + w_ih[2 * n] * x0 + w_ih[2 * n + 1] * x1;
  }
  float cn = sigm(pre[0]) * tanh_f(pre[2]);
  float h  = sigm(pre[3]) * tanh_f(cn);
  coB[g] = (__bf16)cn;
  A0[g] = (__bf16)h;
  if (r == 4096) ht0[j] = h;
}

__global__ __launch_bounds__(256) void pack_w(
    const float* __restrict__ w_hh, const float* __restrict__ wk,
    const float* __restrict__ wv,   const float* __restrict__ wq,
    __bf16* __restrict__ Wp)
{
  int o = blockIdx.x * 256 + threadIdx.x;   // 1,835,008
  int j = o & 7, nn = (o >> 3) & 15, kg = (o >> 7) & 63, ntg = o >> 13;
  int n = ntg * 16 + nn, k = kg * 8 + j;
  float v;
  if (n < 2048)      { int u = n >> 2, g = n & 3; v = w_hh[(g * 512 + u) * 512 + k]; }
  else if (n < 2560) v = wk[(n - 2048) * 512 + k];
  else if (n < 3072) v = wv[(n - 2560) * 512 + k];
  else               v = wq[(n - 3072) * 512 + k];
  Wp[o] = (__bf16)v;
}

__global__ __launch_bounds__(256) void pack_misc(
    const float* __restrict__ b_ih, const float* __restrict__ b_hh,
    const float* __restrict__ w_ih,
    const float* __restrict__ bk, const float* __restrict__ bv,
    const float* __restrict__ bq,
    float* __restrict__ bs, float* __restrict__ w0, float* __restrict__ w1,
    float* __restrict__ biasz)
{
  int i = blockIdx.x * 256 + threadIdx.x;
  if (i < 2048) {
    int u = i >> 2, g = i & 3, n = g * 512 + u;
    bs[i] = b_ih[n] + b_hh[n];
    w0[i] = w_ih[2 * n];
    w1[i] = w_ih[2 * n + 1];
  } else if (i < 2048 + 1536) {
    int z = i - 2048;
    biasz[z] = (z < 512) ? bk[z] : (z < 1024 ? bv[z - 512] : bq[z - 1024]);
  }
}

__global__ __launch_bounds__(256) void scene1_kernel(
    const int* __restrict__ map, const float* __restrict__ emb,
    const float* __restrict__ w1, const float* __restrict__ b1,
    float* __restrict__ out1)
{
  __shared__ float wl[576];
  __shared__ float bl[16];
  const int t = threadIdx.x;
  for (int i = t; i < 576; i += 256) wl[i] = w1[i];
  if (t < 16) bl[t] = b1[t];
  __syncthreads();
  const int y = blockIdx.x, x = t;
  float nb[4][9];
#pragma unroll
  for (int dy = 0; dy < 3; ++dy)
#pragma unroll
    for (int dx = 0; dx < 3; ++dx) {
      int yy = y + dy - 1, xx = x + dx - 1;
      bool ok = (yy >= 0 && yy < 256 && xx >= 0 && xx < 256);
      int m = ok ? map[yy * 256 + xx] : 0;
#pragma unroll
      for (int c = 0; c < 4; ++c)
        nb[c][dy * 3 + dx] = ok ? emb[m * 4 + c] : 0.f;
    }
  for (int oc = 0; oc < 16; ++oc) {
    float a = bl[oc];
#pragma unroll
    for (int c = 0; c < 4; ++c)
#pragma unroll
      for (int k = 0; k < 9; ++k) a += wl[(oc * 4 + c) * 9 + k] * nb[c][k];
    out1[oc * 65536 + y * 256 + x] = fmaxf(a, 0.f);
  }
}

__global__ __launch_bounds__(256) void scene2_kernel(
    const float* __restrict__ out1, const float* __restrict__ w2,
    const float* __restrict__ b2, float* __restrict__ rowpart)
{
  __shared__ float wl[1152];
  __shared__ float lds4[4 * 8];
  const int t = threadIdx.x;
  const int y = blockIdx.x & 255, ocg = blockIdx.x >> 8;
  for (int i = t; i < 1152; i += 256) wl[i] = w2[ocg * 1152 + i];
  __syncthreads();
  const int x = t;
  float acc[8];
#pragma unroll
  for (int o = 0; o < 8; ++o) acc[o] = b2[ocg * 8 + o];
  for (int ic = 0; ic < 16; ++ic) {
    float nb[9];
#pragma unroll
    for (int dy = 0; dy < 3; ++dy)
#pragma unroll
      for (int dx = 0; dx < 3; ++dx) {
        int yy = y + dy - 1, xx = x + dx - 1;
        bool ok = (yy >= 0 && yy < 256 && xx >= 0 && xx < 256);
        nb[dy * 3 + dx] = ok ? out1[ic * 65536 + yy * 256 + xx] : 0.f;
      }
#pragma unroll
    for (int o = 0; o < 8; ++o) {
      const float* w = &wl[(o * 16 + ic) * 9];
#pragma unroll
      for (int k = 0; k < 9; ++k) acc[o] += w[k] * nb[k];
    }
  }
  const int wave = t >> 6, lane = t & 63;
#pragma unroll
  for (int o = 0; o < 8; ++o) {
    float v = fmaxf(acc[o], 0.f);
#pragma unroll
    for (int m = 1; m < 64; m <<= 1) v += __shfl_xor(v, m, 64);
    if (lane == 0) lds4[wave * 8 + o] = v;
  }
  __syncthreads();
  if (t < 8)
    rowpart[y * 32 + ocg * 8 + t] = lds4[t] + lds4[8 + t] + lds4[16 + t] + lds4[24 + t];
}

__global__ __launch_bounds__(512) void scene3_kernel(
    const float* __restrict__ rowpart, const float* __restrict__ fcw,
    const float* __restrict__ fcb, float* __restrict__ scene)
{
  __shared__ float mean[32];
  const int t = threadIdx.x;
  if (t < 32) {
    float s = 0.f;
    for (int y = 0; y < 256; ++y) s += rowpart[y * 32 + t];
    mean[t] = s * (1.f / 65536.f);
  }
  __syncthreads();
  float a = fcb[t];
#pragma unroll
  for (int c = 0; c < 32; ++c) a += mean[c] * fcw[t * 32 + c];
  scene[t] = a;
}

// ---------------------------------------------------------------------------
extern "C" void kernel_launch(void* const* d_in, const int* in_sizes, int n_in,
                              void* d_out, int out_size, void* d_ws, size_t ws_size,
                              hipStream_t stream) {
  const float* target    = (const float*)d_in[0];
  const float* others    = (const float*)d_in[1];
  const int*   scene_map = (const int*)d_in[2];
  const float* emb       = (const float*)d_in[3];
  const float* c1w       = (const float*)d_in[4];
  const float* c1b       = (const float*)d_in[5];
  const float* c2w       = (const float*)d_in[6];
  const float* c2b       = (const float*)d_in[7];
  const float* fcw       = (const float*)d_in[8];
  const float* fcb       = (const float*)d_in[9];
  const float* w_ih      = (const float*)d_in[10];
  const float* w_hh      = (const float*)d_in[11];
  const float* b_ih      = (const float*)d_in[12];
  const float* b_hh      = (const float*)d_in[13];
  const float* wq        = (const float*)d_in[14];
  const float* bq        = (const float*)d_in[15];
  const float* wk        = (const float*)d_in[16];
  const float* bk        = (const float*)d_in[17];
  const float* wv        = (const float*)d_in[18];
  const float* bv        = (const float*)d_in[19];
  const float* out_w     = (const float*)d_in[20];
  const float* out_b     = (const float*)d_in[21];
  float* out = (float*)d_out;

  char* ws = (char*)d_ws;
  size_t off = 0;
  auto alloc = [&](size_t bytes) { size_t o = off; off += (bytes + 255) & ~(size_t)255; return o; };
  __bf16* Zb0   = (__bf16*)(ws + alloc((size_t)4096 * 1024 * 2));
  __bf16* Zb1   = (__bf16*)(ws + alloc((size_t)4096 * 1024 * 2));
  float*  q0    = (float*)(ws + alloc(512 * 4));
  float*  q1    = (float*)(ws + alloc(512 * 4));
  __bf16* Wp    = (__bf16*)(ws + alloc((size_t)1835008 * 2));
  __bf16* A0    = (__bf16*)(ws + alloc((size_t)4224 * 512 * 2));
  __bf16* A1    = (__bf16*)(ws + alloc((size_t)4224 * 512 * 2));
  __bf16* coB   = (__bf16*)(ws + alloc((size_t)4224 * 512 * 2));
  float*  ht    = (float*)(ws + alloc((size_t)65 * 512 * 4));
  float*  scene = (float*)(ws + alloc(2048));
  float*  part  = (float*)(ws + alloc(64 * 513 * 4));
  unsigned int* cnt = (unsigned int*)(ws + alloc(256));
  float*  bs    = (float*)(ws + alloc(2048 * 4));
  float*  w0p   = (float*)(ws + alloc(2048 * 4));
  float*  w1p   = (float*)(ws + alloc(2048 * 4));
  float*  biasz = (float*)(ws + alloc(1536 * 4));
  float*  out1  = (float*)(ws + alloc((size_t)16 * 65536 * 4));
  float*  rowp  = (float*)(ws + alloc(256 * 32 * 4));

  pack_w<<<7168, 256, 0, stream>>>(w_hh, wk, wv, wq, Wp);
  pack_misc<<<14, 256, 0, stream>>>(b_ih, b_hh, w_ih, bk, bv, bq, bs, w0p, w1p, biasz);
  scene1_kernel<<<256, 256, 0, stream>>>(scene_map, emb, c1w, c1b, out1);
  scene2_kernel<<<1024, 256, 0, stream>>>(out1, c2w, c2b, rowp);
  scene3_kernel<<<1, 512, 0, stream>>>(rowp, fcw, fcb, scene);
  init_state<<<8194, 256, 0, stream>>>(others, target, w_ih, b_ih, b_hh, coB, A0, ht, cnt);

  SP hp;
  hp.Wp = (const unsigned short*)Wp;
  hp.A0 = (unsigned short*)A0; hp.A1 = (unsigned short*)A1;
  hp.Zb0 = Zb0; hp.Zb1 = Zb1;
  hp.q0 = q0; hp.q1 = q1;
  hp.coB = coB; hp.ht = ht;
  hp.biasz = biasz;
  hp.bs4 = (const float4*)bs; hp.w04 = (const float4*)w0p; hp.w14 = (const float4*)w1p;
  hp.others = others; hp.target = target;
  hp.scene = scene; hp.out_w = out_w; hp.out_b = out_b;
  hp.part = part; hp.cnt = cnt;
  hp.out = out;

  for (int p = 0; p < 64; ++p)
    step_kernel<<<458, 512, 0, stream>>>(hp, p);
  att_step<<<64, 512, 0, stream>>>(hp, 63);
}

// Round 7
// 1735.664 us; speedup vs baseline: 4.1647x; 1.5486x over previous
//
#include <hip/hip_runtime.h>
#include <hip/hip_bf16.h>

// ---------------------------------------------------------------------------
// Sophie on MI355X, round 22 = R16 base (256 thr, 4 waves, BK=128, 2184us)
// + two L2-traffic fixes:
// 1) FENCE-FREE att: part via agent-scope stores/loads (R5-proven protocol),
//    threadfences DELETED -> removes 65 mid-step L2 invalidations that were
//    dropping B/A lines under the concurrent GEMM blocks every step.
// 2) 2D XCD decode: 4 bm-groups x 2 j-parity cells (56 blocks each + 10
//    tail). Each XCD reads 6 B-slices (~1.5MB) instead of all 14 (3.3MB):
//    beyond-L2 reads ~34 -> ~23 MB/step. GEMM load balanced per cell.
// All arithmetic bit-identical to R16.
// ---------------------------------------------------------------------------

typedef __bf16 bf16x8 __attribute__((ext_vector_type(8)));
typedef float  f32x4  __attribute__((ext_vector_type(4)));

#define KD 512

__device__ __forceinline__ void gl_lds16(const void* g, void* l) {
  __builtin_amdgcn_global_load_lds(
      (const __attribute__((address_space(1))) void*)g,
      (__attribute__((address_space(3))) void*)l, 16, 0, 0);
}
__device__ __forceinline__ float sigm(float x) {
  return __builtin_amdgcn_rcpf(1.f + __expf(-x));
}
__device__ __forceinline__ float tanh_f(float x) {
  return 2.f * __builtin_amdgcn_rcpf(1.f + __expf(-2.f * x)) - 1.f;
}
__device__ __forceinline__ float sel4(f32x4 v, int i) {
  float a = (i & 1) ? v[1] : v[0];
  float b = (i & 1) ? v[3] : v[2];
  return (i & 2) ? b : a;
}
__device__ __forceinline__ float pick(int m, float o0, float o1, float o2, float o3) {
  float a = (m & 1) ? o1 : o0;
  float b = (m & 1) ? o3 : o2;
  return (m & 2) ? b : a;
}
// agent-scope (LLC-coherent) helpers for the att part buffer
__device__ __forceinline__ float agent_ldf(const float* p) {
  return __hip_atomic_load(p, __ATOMIC_RELAXED, __HIP_MEMORY_SCOPE_AGENT);
}
__device__ __forceinline__ void agent_stf(float* p, float v) {
  __hip_atomic_store(p, v, __ATOMIC_RELAXED, __HIP_MEMORY_SCOPE_AGENT);
}

struct SP {
  const unsigned short* Wp;        // [224 ntg][64 kg][16 nn][8 j]: gates|wk|wv|wq
  unsigned short* A0; unsigned short* A1;   // [4224][512] bf16
  __bf16* Zb0; __bf16* Zb1;        // [4096][1024] bf16: k|v bias-folded
  float* q0; float* q1;            // [512] fp32 q bias-folded
  __bf16* coB;                     // [4224][512] bf16 cell state
  float* ht;                       // [65][512]
  const float* biasz;              // [1536] bk|bv|bq
  const float4* bs4; const float4* w04; const float4* w14;
  const float* others; const float* target;
  const float* scene; const float* out_w; const float* out_b;
  float* part; unsigned int* cnt;
  float* out;
};

// ---------------------------------------------------------------------------
// One 128x256 GEMM tile for step p + fused epilogue. BK=128. (R16 verbatim)
// ---------------------------------------------------------------------------
__device__ void do_gemm(const SP& P, int p, int bm, int bn)
{
  __shared__ __align__(16) char aLds[2][128 * 128 * 2];   // 2 x 32 KB

  const int tid = threadIdx.x, wave = tid >> 6, lane = tid & 63;
  const unsigned short* A = (p & 1) ? P.A1 : P.A0;
  __bf16* An = (__bf16*)((p & 1) ? P.A0 : P.A1);
  __bf16* Zb = (p & 1) ? P.Zb1 : P.Zb0;
  float* qv  = (p & 1) ? P.q1 : P.q0;
  const int tin = (p + 1 < 31) ? (p + 1) : 31;
  const int tc  = (p + 1 < 63) ? (p + 1) : 63;
  const float* op = P.others + (size_t)tin * 8192;
  const float* tp = P.target + tc * 2;
  float* htn = P.ht + (size_t)(p + 1) * 512;

  const int m0 = bm * 128;
  const int l15 = lane & 15, lq = lane >> 4;

  int aRow[8], aOff[8], ldsOff[8];
#pragma unroll
  for (int j = 0; j < 8; ++j) {
    int chunk = j * 4 + wave;                 // 0..31
    int r = chunk * 4 + (lane >> 4);          // row local 0..127
    int ch = lane & 15;                       // LDS granule slot
    aRow[j]   = m0 + r;
    aOff[j]   = (ch ^ (r & 15)) * 8;          // global elem offset in row
    ldsOff[j] = chunk * 1024;
  }
  const unsigned short* bBase =
      P.Wp + (size_t)(bn * 16 + wave * 4) * 8192 + lq * 128 + l15 * 8;

  f32x4 acc[8][4];
#pragma unroll
  for (int i = 0; i < 8; ++i)
#pragma unroll
    for (int j = 0; j < 4; ++j) acc[i][j] = f32x4{0.f, 0.f, 0.f, 0.f};

  bf16x8 bCur[4], bNext[4];

#pragma unroll
  for (int j = 0; j < 8; ++j)
    gl_lds16(A + (size_t)aRow[j] * KD + aOff[j], aLds[0] + ldsOff[j]);
#pragma unroll
  for (int nt = 0; nt < 4; ++nt)
    bCur[nt] = *(const bf16x8*)(bBase + nt * 8192);     // kc = 0
  __syncthreads();

  for (int it = 0; it < 4; ++it) {
    if (it < 3) {
      const int k1 = (it + 1) * 128;
#pragma unroll
      for (int j = 0; j < 8; ++j)
        gl_lds16(A + (size_t)aRow[j] * KD + k1 + aOff[j],
                 aLds[(it + 1) & 1] + ldsOff[j]);
    }
    const char* buf = aLds[it & 1];
#pragma unroll
    for (int c = 0; c < 4; ++c) {
      const bool hasNext = !(it == 3 && c == 3);
      if (hasNext) {
        const int nkc = it * 4 + c + 1;       // next K-chunk (K=32 units)
#pragma unroll
        for (int nt = 0; nt < 4; ++nt)
          bNext[nt] = *(const bf16x8*)(bBase + nt * 8192 + nkc * 512);
      }
      bf16x8 af[8];
#pragma unroll
      for (int mt = 0; mt < 8; ++mt) {
        int row = mt * 16 + l15;
        int g = (c * 4 + lq) ^ (row & 15);
        af[mt] = *(const bf16x8*)(buf + row * 256 + g * 16);
      }
#pragma unroll
      for (int mt = 0; mt < 8; ++mt)
#pragma unroll
        for (int nt = 0; nt < 4; ++nt)
          acc[mt][nt] = __builtin_amdgcn_mfma_f32_16x16x32_bf16(
              af[mt], bCur[nt], acc[mt][nt], 0, 0, 0);
      if (hasNext) {
#pragma unroll
        for (int nt = 0; nt < 4; ++nt) bCur[nt] = bNext[nt];
      }
    }
    __syncthreads();
  }
  // K-loop done; aLds free for epilogue staging.

  const int rq = lq * 4;

  if (bn >= 12) {
    // ---- q epilogue: row 4096 only (bm==32 tiles) ----
    if (lq == 0) {
#pragma unroll
      for (int nt = 0; nt < 4; ++nt) {
        int qcol = (bn - 12) * 256 + wave * 64 + nt * 16 + l15;
        qv[qcol] = acc[0][nt][0] + P.biasz[1024 + qcol];
      }
    }
    return;
  }

  if (bn >= 8) {
    // ---- k/v epilogue: LDS transpose -> coalesced 16B stores, 2 halves ----
    __bf16* zT = (__bf16*)aLds;          // [64][256] per half (32 KB)
    const int zbase = (bn - 8) * 256;
    float bias[4];
#pragma unroll
    for (int nt = 0; nt < 4; ++nt)
      bias[nt] = P.biasz[zbase + wave * 64 + nt * 16 + l15];
#pragma unroll
    for (int half = 0; half < 2; ++half) {
#pragma unroll
      for (int mt2 = 0; mt2 < 4; ++mt2) {
        int mt = half * 4 + mt2;
#pragma unroll
        for (int nt = 0; nt < 4; ++nt) {
          int ulocal = wave * 64 + nt * 16 + l15;
#pragma unroll
          for (int r = 0; r < 4; ++r) {
            int rloc = mt2 * 16 + rq + r;
            zT[rloc * 256 + ulocal] = (__bf16)(acc[mt][nt][r] + bias[nt]);
          }
        }
      }
      __syncthreads();
      const bf16x8* zc = (const bf16x8*)zT;
#pragma unroll
      for (int i = 0; i < 8; ++i) {
        int idx = i * 256 + tid;
        int rloc = idx >> 5, c8 = idx & 31;
        *(bf16x8*)(Zb + (size_t)(m0 + half * 64 + rloc) * 1024 + zbase + c8 * 8) = zc[idx];
      }
      __syncthreads();
    }
    return;
  }

  // ---- gate epilogue: fused LSTM cell (R13 form) ----
  const int rho = lane & 3, usel = (lane >> 2) & 3;
  const int u0 = bn * 64 + wave * 16;
  float4 bsv[4], w0v[4], w1v[4];
  int uu[4];
#pragma unroll
  for (int nt = 0; nt < 4; ++nt) {
    uu[nt]  = u0 + nt * 4 + usel;
    bsv[nt] = P.bs4[uu[nt]];
    w0v[nt] = P.w04[uu[nt]];
    w1v[nt] = P.w14[uu[nt]];
  }

  if (bm < 32) {
    __bf16* hT = (__bf16*)aLds[0];       // [128][64]
    __bf16* cT = (__bf16*)aLds[1];       // [128][64]
#pragma unroll
    for (int mt = 0; mt < 8; ++mt) {
      int rloc = mt * 16 + rq + rho;
      int row  = m0 + rloc;
      float x0 = op[2 * row], x1 = op[2 * row + 1];
#pragma unroll
      for (int nt = 0; nt < 4; ++nt) {
        f32x4 v = acc[mt][nt];
        float own = sel4(v, rho);
        float r1  = __shfl_xor(sel4(v, rho ^ 1), 1, 64);
        float r2  = __shfl_xor(sel4(v, rho ^ 2), 2, 64);
        float r3  = __shfl_xor(sel4(v, rho ^ 3), 3, 64);
        float g0 = pick(rho,     own, r1, r2, r3);
        float g1 = pick(rho ^ 1, own, r1, r2, r3);
        float g2 = pick(rho ^ 2, own, r1, r2, r3);
        float g3 = pick(rho ^ 3, own, r1, r2, r3);
        float4 bs = bsv[nt], w0 = w0v[nt], w1 = w1v[nt];
        float p0 = g0 + bs.x + w0.x * x0 + w1.x * x1;
        float p1 = g1 + bs.y + w0.y * x0 + w1.y * x1;
        float p2 = g2 + bs.z + w0.z * x0 + w1.z * x1;
        float p3 = g3 + bs.w + w0.w * x0 + w1.w * x1;
        int u = uu[nt];
        size_t ci = (size_t)row * 512 + u;
        float c_old = (float)P.coB[ci];
        float ii = sigm(p0), ff = sigm(p1), gg = tanh_f(p2), oo = sigm(p3);
        float cn = ff * c_old + ii * gg;
        float h  = oo * tanh_f(cn);
        int ulocal = u - bn * 64;
        hT[rloc * 64 + ulocal] = (__bf16)h;
        cT[rloc * 64 + ulocal] = (__bf16)cn;
      }
    }
    __syncthreads();
    const bf16x8* hc = (const bf16x8*)hT;
    const bf16x8* cc = (const bf16x8*)cT;
#pragma unroll
    for (int i = 0; i < 4; ++i) {
      int idx = i * 256 + tid;
      int rloc = idx >> 3, c8 = idx & 7;
      size_t base = (size_t)(m0 + rloc) * 512 + bn * 64 + c8 * 8;
      *(bf16x8*)(An + base)    = hc[idx];
      *(bf16x8*)(P.coB + base) = cc[idx];
    }
    return;
  }

  // bm == 32: only row 4096 valid
#pragma unroll
  for (int mt = 0; mt < 8; ++mt) {
    int row = m0 + mt * 16 + rq + rho;
    bool act = row <= 4096;
    float x0 = 0.f, x1 = 0.f;
    if (act) {
      if (row < 4096) { x0 = op[2 * row]; x1 = op[2 * row + 1]; }
      else            { x0 = tp[0];       x1 = tp[1]; }
    }
#pragma unroll
    for (int nt = 0; nt < 4; ++nt) {
      f32x4 v = acc[mt][nt];
      float own = sel4(v, rho);
      float r1  = __shfl_xor(sel4(v, rho ^ 1), 1, 64);
      float r2  = __shfl_xor(sel4(v, rho ^ 2), 2, 64);
      float r3  = __shfl_xor(sel4(v, rho ^ 3), 3, 64);
      float g0 = pick(rho,     own, r1, r2, r3);
      float g1 = pick(rho ^ 1, own, r1, r2, r3);
      float g2 = pick(rho ^ 2, own, r1, r2, r3);
      float g3 = pick(rho ^ 3, own, r1, r2, r3);
      if (act) {
        float4 bs = bsv[nt], w0 = w0v[nt], w1 = w1v[nt];
        float p0 = g0 + bs.x + w0.x * x0 + w1.x * x1;
        float p1 = g1 + bs.y + w0.y * x0 + w1.y * x1;
        float p2 = g2 + bs.z + w0.z * x0 + w1.z * x1;
        float p3 = g3 + bs.w + w0.w * x0 + w1.w * x1;
        int u = uu[nt];
        size_t ci = (size_t)row * 512 + u;
        float c_old = (float)P.coB[ci];
        float ii = sigm(p0), ff = sigm(p1), gg = tanh_f(p2), oo = sigm(p3);
        float cn = ff * c_old + ii * gg;
        float h  = oo * tanh_f(cn);
        P.coB[ci] = (__bf16)cn;
        An[ci] = (__bf16)h;
        if (row == 4096) htn[u] = h;
      }
    }
  }
}

// ---------------------------------------------------------------------------
// Attention for step p, task b + last-done finalize. FENCE-FREE protocol:
// part via agent-scope stores (LLC write-through), drained by vmcnt(0) +
// syncthreads before the device-scope atomicAdd; finalize reads part via
// agent loads. No __threadfence -> no mid-step L2 invalidation.
// Values and summation order identical to R16.
// ---------------------------------------------------------------------------
__device__ void do_att(const SP& P, int p, int b)
{
  __shared__ __align__(16) float qs[512];
  __shared__ float red[256];
  __shared__ float red2[256];
  __shared__ float es[64];
  __shared__ unsigned int sOld;
  const int t = threadIdx.x;
  const __bf16* Zb = (p & 1) ? P.Zb1 : P.Zb0;
  const float* qv  = (p & 1) ? P.q1 : P.q0;
  const float* ht  = P.ht + (size_t)p * 512;

  for (int c = t; c < 512; c += 256) qs[c] = qv[c];
  __syncthreads();

  const int r0 = b * 64, rl = t >> 2, p4 = t & 3;
  const bf16x8* krow = (const bf16x8*)(Zb + (size_t)(r0 + rl) * 1024);
  float a = 0.f;
  for (int i = p4; i < 64; i += 4) {
    bf16x8 kk = krow[i];
    const float* qq = qs + i * 8;
#pragma unroll
    for (int j = 0; j < 8; ++j) a += (float)kk[j] * qq[j];
  }
  red[t] = a;
  __syncthreads();
  if (t < 64)
    es[t] = __expf((red[4 * t] + red[4 * t + 1] + red[4 * t + 2] + red[4 * t + 3]) *
                   0.04419417382415922f);
  __syncthreads();

  float s0 = 0.f, s1 = 0.f;
  for (int r = 0; r < 64; ++r) {
    const __bf16* vr = Zb + (size_t)(r0 + r) * 1024 + 512;
    float e = es[r];
    s0 += e * (float)vr[t];
    s1 += e * (float)vr[t + 256];
  }
  agent_stf(&P.part[b * 513 + t], s0);
  agent_stf(&P.part[b * 513 + 256 + t], s1);
  if (t == 0) {
    float se = 0.f;
#pragma unroll
    for (int r = 0; r < 64; ++r) se += es[r];
    agent_stf(&P.part[b * 513 + 512], se);
  }
  asm volatile("s_waitcnt vmcnt(0) lgkmcnt(0)" ::: "memory");
  __syncthreads();
  if (t == 0) sOld = atomicAdd(P.cnt, 1u);
  __syncthreads();
  if (sOld == 63) {
    float s = 0.f, s2 = 0.f, se = 0.f;
    for (int bb = 0; bb < 64; ++bb) {
      s  += agent_ldf(&P.part[bb * 513 + t]);
      s2 += agent_ldf(&P.part[bb * 513 + 256 + t]);
      se += agent_ldf(&P.part[bb * 513 + 512]);
    }
    float inv = 1.f / se;
    float va = ht[t] + s * inv + P.scene[t];
    float vb = ht[t + 256] + s2 * inv + P.scene[t + 256];
    red[t]  = va * P.out_w[t]       + vb * P.out_w[t + 256];
    red2[t] = va * P.out_w[512 + t] + vb * P.out_w[768 + t];
    __syncthreads();
    for (int st = 128; st > 0; st >>= 1) {
      if (t < st) { red[t] += red[t + st]; red2[t] += red2[t + st]; }
      __syncthreads();
    }
    if (t == 0) {
      P.out[2 * p]     = red[0]  + P.out_b[0];
      P.out[2 * p + 1] = red2[0] + P.out_b[1];
      *P.cnt = 0;
    }
  }
}

// ---------------------------------------------------------------------------
// Step dispatch: 458 blocks, 2D XCD decode.
// xcd = b&7 -> cell (r = xcd>>1, c = xcd&1); slot = b>>3.
// slot < 56: bm = 8r + slot/7, j = 2*(slot%7) + c.
//   j < 12 -> gemm(bm, j); j in {12,13} -> att task 2*bm + (j-12) @ p-1.
// slot 56 (all xcd): tail ti = xcd -> bn = ti (bm=32 gates).
// slot 57 (xcd 0,1): tail ti = 8+xcd -> bn = 12+xcd (bm=32 q).
// Per XCD: 48 GEMM + 8 att (+1-2 tail) -> balanced; 6 B-slices per XCD.
// ---------------------------------------------------------------------------
__global__ __launch_bounds__(256, 2) void step_kernel(SP P, int p)
{
  const int xcd  = blockIdx.x & 7;
  const int slot = blockIdx.x >> 3;
  if (slot < 56) {
    const int r = xcd >> 1, c = xcd & 1;
    const int bm = 8 * r + slot / 7;
    const int j  = 2 * (slot % 7) + c;
    if (j < 12) {
      do_gemm(P, p, bm, j);
    } else {
      if (p >= 1) do_att(P, p - 1, 2 * bm + (j - 12));
    }
  } else {
    const int ti = (slot == 56) ? xcd : (8 + xcd);
    const int bn = (ti < 8) ? ti : (12 + (ti - 8));
    do_gemm(P, p, 32, bn);
  }
}

__global__ __launch_bounds__(256) void att_step(SP P, int p) {
  do_att(P, p, blockIdx.x);
}

// ---------------------------------------------------------------------------
// Prep kernels (R16 verbatim).
// ---------------------------------------------------------------------------
__global__ __launch_bounds__(256) void init_state(
    const float* __restrict__ others0, const float* __restrict__ target0,
    const float* __restrict__ w_ih, const float* __restrict__ b_ih,
    const float* __restrict__ b_hh,
    __bf16* __restrict__ coB, __bf16* __restrict__ A0, float* __restrict__ ht0,
    unsigned int* __restrict__ cnt)
{
  int g = blockIdx.x * 256 + threadIdx.x;
  if (g == 0) *cnt = 0u;
  if (g >= 4097 * 512) return;
  int r = g >> 9, j = g & 511;
  float x0, x1;
  if (r < 4096) { x0 = others0[2 * r]; x1 = others0[2 * r + 1]; }
  else          { x0 = target0[0];     x1 = target0[1]; }
  float pre[4];
#pragma unroll
  for (int gg = 0; gg < 4; ++gg) {
    int n = gg * 512 + j;
    pre[gg] = b_ih[n] + b_hh[n] + w_ih[2 * n] * x0 + w_ih[2 * n + 1] * x1;
  }
  float cn = sigm(pre[0]) * tanh_f(pre[2]);
  float h  = sigm(pre[3]) * tanh_f(cn);
  coB[g] = (__bf16)cn;
  A0[g] = (__bf16)h;
  if (r == 4096) ht0[j] = h;
}

__global__ __launch_bounds__(256) void pack_w(
    const float* __restrict__ w_hh, const float* __restrict__ wk,
    const float* __restrict__ wv,   const float* __restrict__ wq,
    __bf16* __restrict__ Wp)
{
  int o = blockIdx.x * 256 + threadIdx.x;   // 1,835,008
  int j = o & 7, nn = (o >> 3) & 15, kg = (o >> 7) & 63, ntg = o >> 13;
  int n = ntg * 16 + nn, k = kg * 8 + j;
  float v;
  if (n < 2048)      { int u = n >> 2, g = n & 3; v = w_hh[(g * 512 + u) * 512 + k]; }
  else if (n < 2560) v = wk[(n - 2048) * 512 + k];
  else if (n < 3072) v = wv[(n - 2560) * 512 + k];
  else               v = wq[(n - 3072) * 512 + k];
  Wp[o] = (__bf16)v;
}

__global__ __launch_bounds__(256) void pack_misc(
    const float* __restrict__ b_ih, const float* __restrict__ b_hh,
    const float* __restrict__ w_ih,
    const float* __restrict__ bk, const float* __restrict__ bv,
    const float* __restrict__ bq,
    float* __restrict__ bs, float* __restrict__ w0, float* __restrict__ w1,
    float* __restrict__ biasz)
{
  int i = blockIdx.x * 256 + threadIdx.x;
  if (i < 2048) {
    int u = i >> 2, g = i & 3, n = g * 512 + u;
    bs[i] = b_ih[n] + b_hh[n];
    w0[i] = w_ih[2 * n];
    w1[i] = w_ih[2 * n + 1];
  } else if (i < 2048 + 1536) {
    int z = i - 2048;
    biasz[z] = (z < 512) ? bk[z] : (z < 1024 ? bv[z - 512] : bq[z - 1024]);
  }
}

__global__ __launch_bounds__(256) void scene1_kernel(
    const int* __restrict__ map, const float* __restrict__ emb,
    const float* __restrict__ w1, const float* __restrict__ b1,
    float* __restrict__ out1)
{
  __shared__ float wl[576];
  __shared__ float bl[16];
  const int t = threadIdx.x;
  for (int i = t; i < 576; i += 256) wl[i] = w1[i];
  if (t < 16) bl[t] = b1[t];
  __syncthreads();
  const int y = blockIdx.x, x = t;
  float nb[4][9];
#pragma unroll
  for (int dy = 0; dy < 3; ++dy)
#pragma unroll
    for (int dx = 0; dx < 3; ++dx) {
      int yy = y + dy - 1, xx = x + dx - 1;
      bool ok = (yy >= 0 && yy < 256 && xx >= 0 && xx < 256);
      int m = ok ? map[yy * 256 + xx] : 0;
#pragma unroll
      for (int c = 0; c < 4; ++c)
        nb[c][dy * 3 + dx] = ok ? emb[m * 4 + c] : 0.f;
    }
  for (int oc = 0; oc < 16; ++oc) {
    float a = bl[oc];
#pragma unroll
    for (int c = 0; c < 4; ++c)
#pragma unroll
      for (int k = 0; k < 9; ++k) a += wl[(oc * 4 + c) * 9 + k] * nb[c][k];
    out1[oc * 65536 + y * 256 + x] = fmaxf(a, 0.f);
  }
}

__global__ __launch_bounds__(256) void scene2_kernel(
    const float* __restrict__ out1, const float* __restrict__ w2,
    const float* __restrict__ b2, float* __restrict__ rowpart)
{
  __shared__ float wl[1152];
  __shared__ float lds4[4 * 8];
  const int t = threadIdx.x;
  const int y = blockIdx.x & 255, ocg = blockIdx.x >> 8;
  for (int i = t; i < 1152; i += 256) wl[i] = w2[ocg * 1152 + i];
  __syncthreads();
  const int x = t;
  float acc[8];
#pragma unroll
  for (int o = 0; o < 8; ++o) acc[o] = b2[ocg * 8 + o];
  for (int ic = 0; ic < 16; ++ic) {
    float nb[9];
#pragma unroll
    for (int dy = 0; dy < 3; ++dy)
#pragma unroll
      for (int dx = 0; dx < 3; ++dx) {
        int yy = y + dy - 1, xx = x + dx - 1;
        bool ok = (yy >= 0 && yy < 256 && xx >= 0 && xx < 256);
        nb[dy * 3 + dx] = ok ? out1[ic * 65536 + yy * 256 + xx] : 0.f;
      }
#pragma unroll
    for (int o = 0; o < 8; ++o) {
      const float* w = &wl[(o * 16 + ic) * 9];
#pragma unroll
      for (int k = 0; k < 9; ++k) acc[o] += w[k] * nb[k];
    }
  }
  const int wave = t >> 6, lane = t & 63;
#pragma unroll
  for (int o = 0; o < 8; ++o) {
    float v = fmaxf(acc[o], 0.f);
#pragma unroll
    for (int m = 1; m < 64; m <<= 1) v += __shfl_xor(v, m, 64);
    if (lane == 0) lds4[wave * 8 + o] = v;
  }
  __syncthreads();
  if (t < 8)
    rowpart[y * 32 + ocg * 8 + t] = lds4[t] + lds4[8 + t] + lds4[16 + t] + lds4[24 + t];
}

__global__ __launch_bounds__(512) void scene3_kernel(
    const float* __restrict__ rowpart, const float* __restrict__ fcw,
    const float* __restrict__ fcb, float* __restrict__ scene)
{
  __shared__ float mean[32];
  const int t = threadIdx.x;
  if (t < 32) {
    float s = 0.f;
    for (int y = 0; y < 256; ++y) s += rowpart[y * 32 + t];
    mean[t] = s * (1.f / 65536.f);
  }
  __syncthreads();
  float a = fcb[t];
#pragma unroll
  for (int c = 0; c < 32; ++c) a += mean[c] * fcw[t * 32 + c];
  scene[t] = a;
}

// ---------------------------------------------------------------------------
extern "C" void kernel_launch(void* const* d_in, const int* in_sizes, int n_in,
                              void* d_out, int out_size, void* d_ws, size_t ws_size,
                              hipStream_t stream) {
  const float* target    = (const float*)d_in[0];
  const float* others    = (const float*)d_in[1];
  const int*   scene_map = (const int*)d_in[2];
  const float* emb       = (const float*)d_in[3];
  const float* c1w       = (const float*)d_in[4];
  const float* c1b       = (const float*)d_in[5];
  const float* c2w       = (const float*)d_in[6];
  const float* c2b       = (const float*)d_in[7];
  const float* fcw       = (const float*)d_in[8];
  const float* fcb       = (const float*)d_in[9];
  const float* w_ih      = (const float*)d_in[10];
  const float* w_hh      = (const float*)d_in[11];
  const float* b_ih      = (const float*)d_in[12];
  const float* b_hh      = (const float*)d_in[13];
  const float* wq        = (const float*)d_in[14];
  const float* bq        = (const float*)d_in[15];
  const float* wk        = (const float*)d_in[16];
  const float* bk        = (const float*)d_in[17];
  const float* wv        = (const float*)d_in[18];
  const float* bv        = (const float*)d_in[19];
  const float* out_w     = (const float*)d_in[20];
  const float* out_b     = (const float*)d_in[21];
  float* out = (float*)d_out;

  char* ws = (char*)d_ws;
  size_t off = 0;
  auto alloc = [&](size_t bytes) { size_t o = off; off += (bytes + 255) & ~(size_t)255; return o; };
  __bf16* Zb0   = (__bf16*)(ws + alloc((size_t)4096 * 1024 * 2));
  __bf16* Zb1   = (__bf16*)(ws + alloc((size_t)4096 * 1024 * 2));
  float*  q0    = (float*)(ws + alloc(512 * 4));
  float*  q1    = (float*)(ws + alloc(512 * 4));
  __bf16* Wp    = (__bf16*)(ws + alloc((size_t)1835008 * 2));
  __bf16* A0    = (__bf16*)(ws + alloc((size_t)4224 * 512 * 2));
  __bf16* A1    = (__bf16*)(ws + alloc((size_t)4224 * 512 * 2));
  __bf16* coB   = (__bf16*)(ws + alloc((size_t)4224 * 512 * 2));
  float*  ht    = (float*)(ws + alloc((size_t)65 * 512 * 4));
  float*  scene = (float*)(ws + alloc(2048));
  float*  part  = (float*)(ws + alloc(64 * 513 * 4));
  unsigned int* cnt = (unsigned int*)(ws + alloc(256));
  float*  bs    = (float*)(ws + alloc(2048 * 4));
  float*  w0p   = (float*)(ws + alloc(2048 * 4));
  float*  w1p   = (float*)(ws + alloc(2048 * 4));
  float*  biasz = (float*)(ws + alloc(1536 * 4));
  float*  out1  = (float*)(ws + alloc((size_t)16 * 65536 * 4));
  float*  rowp  = (float*)(ws + alloc(256 * 32 * 4));

  pack_w<<<7168, 256, 0, stream>>>(w_hh, wk, wv, wq, Wp);
  pack_misc<<<14, 256, 0, stream>>>(b_ih, b_hh, w_ih, bk, bv, bq, bs, w0p, w1p, biasz);
  scene1_kernel<<<256, 256, 0, stream>>>(scene_map, emb, c1w, c1b, out1);
  scene2_kernel<<<1024, 256, 0, stream>>>(out1, c2w, c2b, rowp);
  scene3_kernel<<<1, 512, 0, stream>>>(rowp, fcw, fcb, scene);
  init_state<<<8194, 256, 0, stream>>>(others, target, w_ih, b_ih, b_hh, coB, A0, ht, cnt);

  SP hp;
  hp.Wp = (const unsigned short*)Wp;
  hp.A0 = (unsigned short*)A0; hp.A1 = (unsigned short*)A1;
  hp.Zb0 = Zb0; hp.Zb1 = Zb1;
  hp.q0 = q0; hp.q1 = q1;
  hp.coB = coB; hp.ht = ht;
  hp.biasz = biasz;
  hp.bs4 = (const float4*)bs; hp.w04 = (const float4*)w0p; hp.w14 = (const float4*)w1p;
  hp.others = others; hp.target = target;
  hp.scene = scene; hp.out_w = out_w; hp.out_b = out_b;
  hp.part = part; hp.cnt = cnt;
  hp.out = out;

  for (int p = 0; p < 64; ++p)
    step_kernel<<<458, 256, 0, stream>>>(hp, p);
  att_step<<<64, 256, 0, stream>>>(hp, 63);
}

// Round 8
// 1707.578 us; speedup vs baseline: 4.2332x; 1.0164x over previous
//
#include <hip/hip_runtime.h>
#include <hip/hip_bf16.h>

// ---------------------------------------------------------------------------
// Sophie on MI355X, round 23 = R22 (1736us: fence-free att + 2D XCD decode)
// + two latency fixes, arithmetic bit-identical:
// 1) B prefetch depth 2 (bCur/bNext/bNext2, static rotation): each step
//    starts with a cold L2 (launch-boundary invalidate), so B chunk loads
//    are LLC hits (~700-900cy); depth-1 prefetch (~300-500cy cover) stalled
//    early K-chunks. Depth 2 doubles issue-to-use distance.
// 2) k/v epilogue single-pass: zT = [128][256] across both aLds buffers
//    (64KB), one barrier instead of two half-passes with four. Same
//    element->destination mapping (row = m0 + mt*16 + rq + r).
// ---------------------------------------------------------------------------

typedef __bf16 bf16x8 __attribute__((ext_vector_type(8)));
typedef float  f32x4  __attribute__((ext_vector_type(4)));

#define KD 512

__device__ __forceinline__ void gl_lds16(const void* g, void* l) {
  __builtin_amdgcn_global_load_lds(
      (const __attribute__((address_space(1))) void*)g,
      (__attribute__((address_space(3))) void*)l, 16, 0, 0);
}
__device__ __forceinline__ float sigm(float x) {
  return __builtin_amdgcn_rcpf(1.f + __expf(-x));
}
__device__ __forceinline__ float tanh_f(float x) {
  return 2.f * __builtin_amdgcn_rcpf(1.f + __expf(-2.f * x)) - 1.f;
}
__device__ __forceinline__ float sel4(f32x4 v, int i) {
  float a = (i & 1) ? v[1] : v[0];
  float b = (i & 1) ? v[3] : v[2];
  return (i & 2) ? b : a;
}
__device__ __forceinline__ float pick(int m, float o0, float o1, float o2, float o3) {
  float a = (m & 1) ? o1 : o0;
  float b = (m & 1) ? o3 : o2;
  return (m & 2) ? b : a;
}
// agent-scope (LLC-coherent) helpers for the att part buffer
__device__ __forceinline__ float agent_ldf(const float* p) {
  return __hip_atomic_load(p, __ATOMIC_RELAXED, __HIP_MEMORY_SCOPE_AGENT);
}
__device__ __forceinline__ void agent_stf(float* p, float v) {
  __hip_atomic_store(p, v, __ATOMIC_RELAXED, __HIP_MEMORY_SCOPE_AGENT);
}

struct SP {
  const unsigned short* Wp;        // [224 ntg][64 kg][16 nn][8 j]: gates|wk|wv|wq
  unsigned short* A0; unsigned short* A1;   // [4224][512] bf16
  __bf16* Zb0; __bf16* Zb1;        // [4096][1024] bf16: k|v bias-folded
  float* q0; float* q1;            // [512] fp32 q bias-folded
  __bf16* coB;                     // [4224][512] bf16 cell state
  float* ht;                       // [65][512]
  const float* biasz;              // [1536] bk|bv|bq
  const float4* bs4; const float4* w04; const float4* w14;
  const float* others; const float* target;
  const float* scene; const float* out_w; const float* out_b;
  float* part; unsigned int* cnt;
  float* out;
};

// ---------------------------------------------------------------------------
// One 128x256 GEMM tile for step p + fused epilogue. BK=128.
// Flat kc-loop (16 K-chunks of K=32); A double-buffered per 4 chunks;
// B register pipeline depth 2.
// LDS layout: granule g of row r holds k-granule (g ^ (r & 15)).
// ---------------------------------------------------------------------------
__device__ void do_gemm(const SP& P, int p, int bm, int bn)
{
  __shared__ __align__(16) char aLds[2][128 * 128 * 2];   // 2 x 32 KB

  const int tid = threadIdx.x, wave = tid >> 6, lane = tid & 63;
  const unsigned short* A = (p & 1) ? P.A1 : P.A0;
  __bf16* An = (__bf16*)((p & 1) ? P.A0 : P.A1);
  __bf16* Zb = (p & 1) ? P.Zb1 : P.Zb0;
  float* qv  = (p & 1) ? P.q1 : P.q0;
  const int tin = (p + 1 < 31) ? (p + 1) : 31;
  const int tc  = (p + 1 < 63) ? (p + 1) : 63;
  const float* op = P.others + (size_t)tin * 8192;
  const float* tp = P.target + tc * 2;
  float* htn = P.ht + (size_t)(p + 1) * 512;

  const int m0 = bm * 128;
  const int l15 = lane & 15, lq = lane >> 4;

  int aRow[8], aOff[8], ldsOff[8];
#pragma unroll
  for (int j = 0; j < 8; ++j) {
    int chunk = j * 4 + wave;                 // 0..31
    int r = chunk * 4 + (lane >> 4);          // row local 0..127
    int ch = lane & 15;                       // LDS granule slot
    aRow[j]   = m0 + r;
    aOff[j]   = (ch ^ (r & 15)) * 8;          // global elem offset in row
    ldsOff[j] = chunk * 1024;
  }
  const unsigned short* bBase =
      P.Wp + (size_t)(bn * 16 + wave * 4) * 8192 + lq * 128 + l15 * 8;

  f32x4 acc[8][4];
#pragma unroll
  for (int i = 0; i < 8; ++i)
#pragma unroll
    for (int j = 0; j < 4; ++j) acc[i][j] = f32x4{0.f, 0.f, 0.f, 0.f};

  bf16x8 bCur[4], bNext[4], bNext2[4];

#pragma unroll
  for (int j = 0; j < 8; ++j)
    gl_lds16(A + (size_t)aRow[j] * KD + aOff[j], aLds[0] + ldsOff[j]);
#pragma unroll
  for (int nt = 0; nt < 4; ++nt) {
    bCur[nt]  = *(const bf16x8*)(bBase + nt * 8192);          // chunk 0
    bNext[nt] = *(const bf16x8*)(bBase + nt * 8192 + 512);    // chunk 1
  }
  __syncthreads();

#pragma unroll
  for (int kc = 0; kc < 16; ++kc) {
    const int it = kc >> 2, cc = kc & 3;
    if (cc == 0 && it < 3) {
      const int k1 = (it + 1) * 128;
#pragma unroll
      for (int j = 0; j < 8; ++j)
        gl_lds16(A + (size_t)aRow[j] * KD + k1 + aOff[j],
                 aLds[(it + 1) & 1] + ldsOff[j]);
    }
    if (kc + 2 < 16) {
#pragma unroll
      for (int nt = 0; nt < 4; ++nt)
        bNext2[nt] = *(const bf16x8*)(bBase + nt * 8192 + (kc + 2) * 512);
    }
    const char* buf = aLds[it & 1];
    bf16x8 af[8];
#pragma unroll
    for (int mt = 0; mt < 8; ++mt) {
      int row = mt * 16 + l15;
      int g = (cc * 4 + lq) ^ (row & 15);
      af[mt] = *(const bf16x8*)(buf + row * 256 + g * 16);
    }
#pragma unroll
    for (int mt = 0; mt < 8; ++mt)
#pragma unroll
      for (int nt = 0; nt < 4; ++nt)
        acc[mt][nt] = __builtin_amdgcn_mfma_f32_16x16x32_bf16(
            af[mt], bCur[nt], acc[mt][nt], 0, 0, 0);
#pragma unroll
    for (int nt = 0; nt < 4; ++nt) {
      bCur[nt] = bNext[nt];
      bNext[nt] = bNext2[nt];
    }
    if (cc == 3) __syncthreads();
  }
  // K-loop done (last barrier executed at kc=15); aLds free for epilogue.

  const int rq = lq * 4;

  if (bn >= 12) {
    // ---- q epilogue: row 4096 only (bm==32 tiles) ----
    if (lq == 0) {
#pragma unroll
      for (int nt = 0; nt < 4; ++nt) {
        int qcol = (bn - 12) * 256 + wave * 64 + nt * 16 + l15;
        qv[qcol] = acc[0][nt][0] + P.biasz[1024 + qcol];
      }
    }
    return;
  }

  if (bn >= 8) {
    // ---- k/v epilogue: single-pass LDS transpose (64KB) -> 16B stores ----
    __bf16* zT = (__bf16*)aLds;          // [128][256] = 64 KB (both buffers)
    const int zbase = (bn - 8) * 256;
    float bias[4];
#pragma unroll
    for (int nt = 0; nt < 4; ++nt)
      bias[nt] = P.biasz[zbase + wave * 64 + nt * 16 + l15];
#pragma unroll
    for (int mt = 0; mt < 8; ++mt) {
#pragma unroll
      for (int nt = 0; nt < 4; ++nt) {
        int ulocal = wave * 64 + nt * 16 + l15;
#pragma unroll
        for (int r = 0; r < 4; ++r) {
          int rloc = mt * 16 + rq + r;
          zT[rloc * 256 + ulocal] = (__bf16)(acc[mt][nt][r] + bias[nt]);
        }
      }
    }
    __syncthreads();
    const bf16x8* zc = (const bf16x8*)zT;
#pragma unroll
    for (int i = 0; i < 16; ++i) {
      int idx = i * 256 + tid;
      int rloc = idx >> 5, c8 = idx & 31;
      *(bf16x8*)(Zb + (size_t)(m0 + rloc) * 1024 + zbase + c8 * 8) = zc[idx];
    }
    return;
  }

  // ---- gate epilogue: fused LSTM cell (R13 form) ----
  const int rho = lane & 3, usel = (lane >> 2) & 3;
  const int u0 = bn * 64 + wave * 16;
  float4 bsv[4], w0v[4], w1v[4];
  int uu[4];
#pragma unroll
  for (int nt = 0; nt < 4; ++nt) {
    uu[nt]  = u0 + nt * 4 + usel;
    bsv[nt] = P.bs4[uu[nt]];
    w0v[nt] = P.w04[uu[nt]];
    w1v[nt] = P.w14[uu[nt]];
  }

  if (bm < 32) {
    __bf16* hT = (__bf16*)aLds[0];       // [128][64]
    __bf16* cT = (__bf16*)aLds[1];       // [128][64]
#pragma unroll
    for (int mt = 0; mt < 8; ++mt) {
      int rloc = mt * 16 + rq + rho;
      int row  = m0 + rloc;
      float x0 = op[2 * row], x1 = op[2 * row + 1];
#pragma unroll
      for (int nt = 0; nt < 4; ++nt) {
        f32x4 v = acc[mt][nt];
        float own = sel4(v, rho);
        float r1  = __shfl_xor(sel4(v, rho ^ 1), 1, 64);
        float r2  = __shfl_xor(sel4(v, rho ^ 2), 2, 64);
        float r3  = __shfl_xor(sel4(v, rho ^ 3), 3, 64);
        float g0 = pick(rho,     own, r1, r2, r3);
        float g1 = pick(rho ^ 1, own, r1, r2, r3);
        float g2 = pick(rho ^ 2, own, r1, r2, r3);
        float g3 = pick(rho ^ 3, own, r1, r2, r3);
        float4 bs = bsv[nt], w0 = w0v[nt], w1 = w1v[nt];
        float p0 = g0 + bs.x + w0.x * x0 + w1.x * x1;
        float p1 = g1 + bs.y + w0.y * x0 + w1.y * x1;
        float p2 = g2 + bs.z + w0.z * x0 + w1.z * x1;
        float p3 = g3 + bs.w + w0.w * x0 + w1.w * x1;
        int u = uu[nt];
        size_t ci = (size_t)row * 512 + u;
        float c_old = (float)P.coB[ci];
        float ii = sigm(p0), ff = sigm(p1), gg = tanh_f(p2), oo = sigm(p3);
        float cn = ff * c_old + ii * gg;
        float h  = oo * tanh_f(cn);
        int ulocal = u - bn * 64;
        hT[rloc * 64 + ulocal] = (__bf16)h;
        cT[rloc * 64 + ulocal] = (__bf16)cn;
      }
    }
    __syncthreads();
    const bf16x8* hc = (const bf16x8*)hT;
    const bf16x8* cc = (const bf16x8*)cT;
#pragma unroll
    for (int i = 0; i < 4; ++i) {
      int idx = i * 256 + tid;
      int rloc = idx >> 3, c8 = idx & 7;
      size_t base = (size_t)(m0 + rloc) * 512 + bn * 64 + c8 * 8;
      *(bf16x8*)(An + base)    = hc[idx];
      *(bf16x8*)(P.coB + base) = cc[idx];
    }
    return;
  }

  // bm == 32: only row 4096 valid
#pragma unroll
  for (int mt = 0; mt < 8; ++mt) {
    int row = m0 + mt * 16 + rq + rho;
    bool act = row <= 4096;
    float x0 = 0.f, x1 = 0.f;
    if (act) {
      if (row < 4096) { x0 = op[2 * row]; x1 = op[2 * row + 1]; }
      else            { x0 = tp[0];       x1 = tp[1]; }
    }
#pragma unroll
    for (int nt = 0; nt < 4; ++nt) {
      f32x4 v = acc[mt][nt];
      float own = sel4(v, rho);
      float r1  = __shfl_xor(sel4(v, rho ^ 1), 1, 64);
      float r2  = __shfl_xor(sel4(v, rho ^ 2), 2, 64);
      float r3  = __shfl_xor(sel4(v, rho ^ 3), 3, 64);
      float g0 = pick(rho,     own, r1, r2, r3);
      float g1 = pick(rho ^ 1, own, r1, r2, r3);
      float g2 = pick(rho ^ 2, own, r1, r2, r3);
      float g3 = pick(rho ^ 3, own, r1, r2, r3);
      if (act) {
        float4 bs = bsv[nt], w0 = w0v[nt], w1 = w1v[nt];
        float p0 = g0 + bs.x + w0.x * x0 + w1.x * x1;
        float p1 = g1 + bs.y + w0.y * x0 + w1.y * x1;
        float p2 = g2 + bs.z + w0.z * x0 + w1.z * x1;
        float p3 = g3 + bs.w + w0.w * x0 + w1.w * x1;
        int u = uu[nt];
        size_t ci = (size_t)row * 512 + u;
        float c_old = (float)P.coB[ci];
        float ii = sigm(p0), ff = sigm(p1), gg = tanh_f(p2), oo = sigm(p3);
        float cn = ff * c_old + ii * gg;
        float h  = oo * tanh_f(cn);
        P.coB[ci] = (__bf16)cn;
        An[ci] = (__bf16)h;
        if (row == 4096) htn[u] = h;
      }
    }
  }
}

// ---------------------------------------------------------------------------
// Attention for step p, task b + last-done finalize. FENCE-FREE (R22).
// ---------------------------------------------------------------------------
__device__ void do_att(const SP& P, int p, int b)
{
  __shared__ __align__(16) float qs[512];
  __shared__ float red[256];
  __shared__ float red2[256];
  __shared__ float es[64];
  __shared__ unsigned int sOld;
  const int t = threadIdx.x;
  const __bf16* Zb = (p & 1) ? P.Zb1 : P.Zb0;
  const float* qv  = (p & 1) ? P.q1 : P.q0;
  const float* ht  = P.ht + (size_t)p * 512;

  for (int c = t; c < 512; c += 256) qs[c] = qv[c];
  __syncthreads();

  const int r0 = b * 64, rl = t >> 2, p4 = t & 3;
  const bf16x8* krow = (const bf16x8*)(Zb + (size_t)(r0 + rl) * 1024);
  float a = 0.f;
  for (int i = p4; i < 64; i += 4) {
    bf16x8 kk = krow[i];
    const float* qq = qs + i * 8;
#pragma unroll
    for (int j = 0; j < 8; ++j) a += (float)kk[j] * qq[j];
  }
  red[t] = a;
  __syncthreads();
  if (t < 64)
    es[t] = __expf((red[4 * t] + red[4 * t + 1] + red[4 * t + 2] + red[4 * t + 3]) *
                   0.04419417382415922f);
  __syncthreads();

  float s0 = 0.f, s1 = 0.f;
  for (int r = 0; r < 64; ++r) {
    const __bf16* vr = Zb + (size_t)(r0 + r) * 1024 + 512;
    float e = es[r];
    s0 += e * (float)vr[t];
    s1 += e * (float)vr[t + 256];
  }
  agent_stf(&P.part[b * 513 + t], s0);
  agent_stf(&P.part[b * 513 + 256 + t], s1);
  if (t == 0) {
    float se = 0.f;
#pragma unroll
    for (int r = 0; r < 64; ++r) se += es[r];
    agent_stf(&P.part[b * 513 + 512], se);
  }
  asm volatile("s_waitcnt vmcnt(0) lgkmcnt(0)" ::: "memory");
  __syncthreads();
  if (t == 0) sOld = atomicAdd(P.cnt, 1u);
  __syncthreads();
  if (sOld == 63) {
    float s = 0.f, s2 = 0.f, se = 0.f;
    for (int bb = 0; bb < 64; ++bb) {
      s  += agent_ldf(&P.part[bb * 513 + t]);
      s2 += agent_ldf(&P.part[bb * 513 + 256 + t]);
      se += agent_ldf(&P.part[bb * 513 + 512]);
    }
    float inv = 1.f / se;
    float va = ht[t] + s * inv + P.scene[t];
    float vb = ht[t + 256] + s2 * inv + P.scene[t + 256];
    red[t]  = va * P.out_w[t]       + vb * P.out_w[t + 256];
    red2[t] = va * P.out_w[512 + t] + vb * P.out_w[768 + t];
    __syncthreads();
    for (int st = 128; st > 0; st >>= 1) {
      if (t < st) { red[t] += red[t + st]; red2[t] += red2[t + st]; }
      __syncthreads();
    }
    if (t == 0) {
      P.out[2 * p]     = red[0]  + P.out_b[0];
      P.out[2 * p + 1] = red2[0] + P.out_b[1];
      *P.cnt = 0;
    }
  }
}

// ---------------------------------------------------------------------------
// Step dispatch: 458 blocks, 2D XCD decode (R22).
// xcd = b&7 -> cell (r = xcd>>1, c = xcd&1); slot = b>>3.
// slot < 56: bm = 8r + slot/7, j = 2*(slot%7) + c.
//   j < 12 -> gemm(bm, j); j in {12,13} -> att task 2*bm + (j-12) @ p-1.
// slot 56 (all xcd): tail bn = xcd (bm=32). slot 57 (xcd 0,1): bn = 12+xcd.
// ---------------------------------------------------------------------------
__global__ __launch_bounds__(256, 2) void step_kernel(SP P, int p)
{
  const int xcd  = blockIdx.x & 7;
  const int slot = blockIdx.x >> 3;
  if (slot < 56) {
    const int r = xcd >> 1, c = xcd & 1;
    const int bm = 8 * r + slot / 7;
    const int j  = 2 * (slot % 7) + c;
    if (j < 12) {
      do_gemm(P, p, bm, j);
    } else {
      if (p >= 1) do_att(P, p - 1, 2 * bm + (j - 12));
    }
  } else {
    const int ti = (slot == 56) ? xcd : (8 + xcd);
    const int bn = (ti < 8) ? ti : (12 + (ti - 8));
    do_gemm(P, p, 32, bn);
  }
}

__global__ __launch_bounds__(256) void att_step(SP P, int p) {
  do_att(P, p, blockIdx.x);
}

// ---------------------------------------------------------------------------
// Prep kernels (R16 verbatim).
// ---------------------------------------------------------------------------
__global__ __launch_bounds__(256) void init_state(
    const float* __restrict__ others0, const float* __restrict__ target0,
    const float* __restrict__ w_ih, const float* __restrict__ b_ih,
    const float* __restrict__ b_hh,
    __bf16* __restrict__ coB, __bf16* __restrict__ A0, float* __restrict__ ht0,
    unsigned int* __restrict__ cnt)
{
  int g = blockIdx.x * 256 + threadIdx.x;
  if (g == 0) *cnt = 0u;
  if (g >= 4097 * 512) return;
  int r = g >> 9, j = g & 511;
  float x0, x1;
  if (r < 4096) { x0 = others0[2 * r]; x1 = others0[2 * r + 1]; }
  else          { x0 = target0[0];     x1 = target0[1]; }
  float pre[4];
#pragma unroll
  for (int gg = 0; gg < 4; ++gg) {
    int n = gg * 512 + j;
    pre[gg] = b_ih[n] + b_hh[n] + w_ih[2 * n] * x0 + w_ih[2 * n + 1] * x1;
  }
  float cn = sigm(pre[0]) * tanh_f(pre[2]);
  float h  = sigm(pre[3]) * tanh_f(cn);
  coB[g] = (__bf16)cn;
  A0[g] = (__bf16)h;
  if (r == 4096) ht0[j] = h;
}

__global__ __launch_bounds__(256) void pack_w(
    const float* __restrict__ w_hh, const float* __restrict__ wk,
    const float* __restrict__ wv,   const float* __restrict__ wq,
    __bf16* __restrict__ Wp)
{
  int o = blockIdx.x * 256 + threadIdx.x;   // 1,835,008
  int j = o & 7, nn = (o >> 3) & 15, kg = (o >> 7) & 63, ntg = o >> 13;
  int n = ntg * 16 + nn, k = kg * 8 + j;
  float v;
  if (n < 2048)      { int u = n >> 2, g = n & 3; v = w_hh[(g * 512 + u) * 512 + k]; }
  else if (n < 2560) v = wk[(n - 2048) * 512 + k];
  else if (n < 3072) v = wv[(n - 2560) * 512 + k];
  else               v = wq[(n - 3072) * 512 + k];
  Wp[o] = (__bf16)v;
}

__global__ __launch_bounds__(256) void pack_misc(
    const float* __restrict__ b_ih, const float* __restrict__ b_hh,
    const float* __restrict__ w_ih,
    const float* __restrict__ bk, const float* __restrict__ bv,
    const float* __restrict__ bq,
    float* __restrict__ bs, float* __restrict__ w0, float* __restrict__ w1,
    float* __restrict__ biasz)
{
  int i = blockIdx.x * 256 + threadIdx.x;
  if (i < 2048) {
    int u = i >> 2, g = i & 3, n = g * 512 + u;
    bs[i] = b_ih[n] + b_hh[n];
    w0[i] = w_ih[2 * n];
    w1[i] = w_ih[2 * n + 1];
  } else if (i < 2048 + 1536) {
    int z = i - 2048;
    biasz[z] = (z < 512) ? bk[z] : (z < 1024 ? bv[z - 512] : bq[z - 1024]);
  }
}

__global__ __launch_bounds__(256) void scene1_kernel(
    const int* __restrict__ map, const float* __restrict__ emb,
    const float* __restrict__ w1, const float* __restrict__ b1,
    float* __restrict__ out1)
{
  __shared__ float wl[576];
  __shared__ float bl[16];
  const int t = threadIdx.x;
  for (int i = t; i < 576; i += 256) wl[i] = w1[i];
  if (t < 16) bl[t] = b1[t];
  __syncthreads();
  const int y = blockIdx.x, x = t;
  float nb[4][9];
#pragma unroll
  for (int dy = 0; dy < 3; ++dy)
#pragma unroll
    for (int dx = 0; dx < 3; ++dx) {
      int yy = y + dy - 1, xx = x + dx - 1;
      bool ok = (yy >= 0 && yy < 256 && xx >= 0 && xx < 256);
      int m = ok ? map[yy * 256 + xx] : 0;
#pragma unroll
      for (int c = 0; c < 4; ++c)
        nb[c][dy * 3 + dx] = ok ? emb[m * 4 + c] : 0.f;
    }
  for (int oc = 0; oc < 16; ++oc) {
    float a = bl[oc];
#pragma unroll
    for (int c = 0; c < 4; ++c)
#pragma unroll
      for (int k = 0; k < 9; ++k) a += wl[(oc * 4 + c) * 9 + k] * nb[c][k];
    out1[oc * 65536 + y * 256 + x] = fmaxf(a, 0.f);
  }
}

__global__ __launch_bounds__(256) void scene2_kernel(
    const float* __restrict__ out1, const float* __restrict__ w2,
    const float* __restrict__ b2, float* __restrict__ rowpart)
{
  __shared__ float wl[1152];
  __shared__ float lds4[4 * 8];
  const int t = threadIdx.x;
  const int y = blockIdx.x & 255, ocg = blockIdx.x >> 8;
  for (int i = t; i < 1152; i += 256) wl[i] = w2[ocg * 1152 + i];
  __syncthreads();
  const int x = t;
  float acc[8];
#pragma unroll
  for (int o = 0; o < 8; ++o) acc[o] = b2[ocg * 8 + o];
  for (int ic = 0; ic < 16; ++ic) {
    float nb[9];
#pragma unroll
    for (int dy = 0; dy < 3; ++dy)
#pragma unroll
      for (int dx = 0; dx < 3; ++dx) {
        int yy = y + dy - 1, xx = x + dx - 1;
        bool ok = (yy >= 0 && yy < 256 && xx >= 0 && xx < 256);
        nb[dy * 3 + dx] = ok ? out1[ic * 65536 + yy * 256 + xx] : 0.f;
      }
#pragma unroll
    for (int o = 0; o < 8; ++o) {
      const float* w = &wl[(o * 16 + ic) * 9];
#pragma unroll
      for (int k = 0; k < 9; ++k) acc[o] += w[k] * nb[k];
    }
  }
  const int wave = t >> 6, lane = t & 63;
#pragma unroll
  for (int o = 0; o < 8; ++o) {
    float v = fmaxf(acc[o], 0.f);
#pragma unroll
    for (int m = 1; m < 64; m <<= 1) v += __shfl_xor(v, m, 64);
    if (lane == 0) lds4[wave * 8 + o] = v;
  }
  __syncthreads();
  if (t < 8)
    rowpart[y * 32 + ocg * 8 + t] = lds4[t] + lds4[8 + t] + lds4[16 + t] + lds4[24 + t];
}

__global__ __launch_bounds__(512) void scene3_kernel(
    const float* __restrict__ rowpart, const float* __restrict__ fcw,
    const float* __restrict__ fcb, float* __restrict__ scene)
{
  __shared__ float mean[32];
  const int t = threadIdx.x;
  if (t < 32) {
    float s = 0.f;
    for (int y = 0; y < 256; ++y) s += rowpart[y * 32 + t];
    mean[t] = s * (1.f / 65536.f);
  }
  __syncthreads();
  float a = fcb[t];
#pragma unroll
  for (int c = 0; c < 32; ++c) a += mean[c] * fcw[t * 32 + c];
  scene[t] = a;
}

// ---------------------------------------------------------------------------
extern "C" void kernel_launch(void* const* d_in, const int* in_sizes, int n_in,
                              void* d_out, int out_size, void* d_ws, size_t ws_size,
                              hipStream_t stream) {
  const float* target    = (const float*)d_in[0];
  const float* others    = (const float*)d_in[1];
  const int*   scene_map = (const int*)d_in[2];
  const float* emb       = (const float*)d_in[3];
  const float* c1w       = (const float*)d_in[4];
  const float* c1b       = (const float*)d_in[5];
  const float* c2w       = (const float*)d_in[6];
  const float* c2b       = (const float*)d_in[7];
  const float* fcw       = (const float*)d_in[8];
  const float* fcb       = (const float*)d_in[9];
  const float* w_ih      = (const float*)d_in[10];
  const float* w_hh      = (const float*)d_in[11];
  const float* b_ih      = (const float*)d_in[12];
  const float* b_hh      = (const float*)d_in[13];
  const float* wq        = (const float*)d_in[14];
  const float* bq        = (const float*)d_in[15];
  const float* wk        = (const float*)d_in[16];
  const float* bk        = (const float*)d_in[17];
  const float* wv        = (const float*)d_in[18];
  const float* bv        = (const float*)d_in[19];
  const float* out_w     = (const float*)d_in[20];
  const float* out_b     = (const float*)d_in[21];
  float* out = (float*)d_out;

  char* ws = (char*)d_ws;
  size_t off = 0;
  auto alloc = [&](size_t bytes) { size_t o = off; off += (bytes + 255) & ~(size_t)255; return o; };
  __bf16* Zb0   = (__bf16*)(ws + alloc((size_t)4096 * 1024 * 2));
  __bf16* Zb1   = (__bf16*)(ws + alloc((size_t)4096 * 1024 * 2));
  float*  q0    = (float*)(ws + alloc(512 * 4));
  float*  q1    = (float*)(ws + alloc(512 * 4));
  __bf16* Wp    = (__bf16*)(ws + alloc((size_t)1835008 * 2));
  __bf16* A0    = (__bf16*)(ws + alloc((size_t)4224 * 512 * 2));
  __bf16* A1    = (__bf16*)(ws + alloc((size_t)4224 * 512 * 2));
  __bf16* coB   = (__bf16*)(ws + alloc((size_t)4224 * 512 * 2));
  float*  ht    = (float*)(ws + alloc((size_t)65 * 512 * 4));
  float*  scene = (float*)(ws + alloc(2048));
  float*  part  = (float*)(ws + alloc(64 * 513 * 4));
  unsigned int* cnt = (unsigned int*)(ws + alloc(256));
  float*  bs    = (float*)(ws + alloc(2048 * 4));
  float*  w0p   = (float*)(ws + alloc(2048 * 4));
  float*  w1p   = (float*)(ws + alloc(2048 * 4));
  float*  biasz = (float*)(ws + alloc(1536 * 4));
  float*  out1  = (float*)(ws + alloc((size_t)16 * 65536 * 4));
  float*  rowp  = (float*)(ws + alloc(256 * 32 * 4));

  pack_w<<<7168, 256, 0, stream>>>(w_hh, wk, wv, wq, Wp);
  pack_misc<<<14, 256, 0, stream>>>(b_ih, b_hh, w_ih, bk, bv, bq, bs, w0p, w1p, biasz);
  scene1_kernel<<<256, 256, 0, stream>>>(scene_map, emb, c1w, c1b, out1);
  scene2_kernel<<<1024, 256, 0, stream>>>(out1, c2w, c2b, rowp);
  scene3_kernel<<<1, 512, 0, stream>>>(rowp, fcw, fcb, scene);
  init_state<<<8194, 256, 0, stream>>>(others, target, w_ih, b_ih, b_hh, coB, A0, ht, cnt);

  SP hp;
  hp.Wp = (const unsigned short*)Wp;
  hp.A0 = (unsigned short*)A0; hp.A1 = (unsigned short*)A1;
  hp.Zb0 = Zb0; hp.Zb1 = Zb1;
  hp.q0 = q0; hp.q1 = q1;
  hp.coB = coB; hp.ht = ht;
  hp.biasz = biasz;
  hp.bs4 = (const float4*)bs; hp.w04 = (const float4*)w0p; hp.w14 = (const float4*)w1p;
  hp.others = others; hp.target = target;
  hp.scene = scene; hp.out_w = out_w; hp.out_b = out_b;
  hp.part = part; hp.cnt = cnt;
  hp.out = out;

  for (int p = 0; p < 64; ++p)
    step_kernel<<<458, 256, 0, stream>>>(hp, p);
  att_step<<<64, 256, 0, stream>>>(hp, 63);
}